// Round 14
// baseline (868.906 us; speedup 1.0000x reference)
//
#include <hip/hip_runtime.h>

// S=1024, T=64, F=128, J=64, E=256, H=4, DH=64. M = S*T = 65536 rows.
// r14: k_ffn7 — LDS-resident weight chunks (zero mid-loop global loads),
// grid 256, 256 rows/block, acc2 held across chunks. LN hoisted to k_lnh.

typedef _Float16 h16;
typedef __attribute__((ext_vector_type(8))) _Float16 f16x8;
typedef __attribute__((ext_vector_type(4))) _Float16 f16x4;
typedef __attribute__((ext_vector_type(4))) float f32x4;

__device__ inline float wave_sum(float v){
  #pragma unroll
  for (int o=32;o;o>>=1) v += __shfl_xor(v,o);
  return v;
}
__device__ inline float wave_max(float v){
  #pragma unroll
  for (int o=32;o;o>>=1) v = fmaxf(v,__shfl_xor(v,o));
  return v;
}

// ---------------------------------------------------------------- pe table
__global__ __launch_bounds__(256) void k_pe(float* __restrict__ pe){
  int t = blockIdx.x, i = threadIdx.x;
  float two_i = (float)((i>>1)<<1);
  float dv = powf(100004.0f, two_i*(1.0f/256.0f));
  float v = (float)t / dv;
  pe[t*256+i] = (i&1) ? cosf(v) : sinf(v);
}

// ---------------------------------------------------------------- gate softmax
__global__ __launch_bounds__(64) void k_gate(const float* __restrict__ x,
    const float* __restrict__ gW, const float* __restrict__ gb,
    float* __restrict__ gate){
  int s = blockIdx.x, lane = threadIdx.x;
  __shared__ float xg[64];
  xg[lane] = x[((size_t)s*64+63)*192 + 128 + lane];
  __syncthreads();
  float a0 = gb[lane], a1 = gb[64+lane];
  #pragma unroll 4
  for (int j=0;j<64;j++){
    float xv = xg[j];
    a0 += xv*gW[j*128+lane];
    a1 += xv*gW[j*128+64+lane];
  }
  float mx = wave_max(fmaxf(a0,a1));
  float e0 = __expf(a0-mx), e1 = __expf(a1-mx);
  float sm = wave_sum(e0+e1);
  gate[s*128+lane]    = e0/sm;
  gate[s*128+64+lane] = e1/sm;
}

// ---------------------------------------------------------------- all weight transposes -> f16 [n][k]
__global__ __launch_bounds__(256) void k_t16all(
    const float* __restrict__ q1, const float* __restrict__ k1, const float* __restrict__ v1,
    const float* __restrict__ q2, const float* __restrict__ k2, const float* __restrict__ v2,
    const float* __restrict__ embed_W, const float* __restrict__ temp_W,
    const float* __restrict__ iW1, const float* __restrict__ iW2,
    const float* __restrict__ eW1, const float* __restrict__ eW2,
    h16* __restrict__ base){
  __shared__ float tile[32][33];
  const int b = blockIdx.x, tid = threadIdx.x;
  const float* src; h16* dst; int K, N, tb; bool qkv = false;
  if (b < 384){
    int mat = b>>6; tb = b&63; qkv = true; K = 256; N = 256;
    src = (mat==0)?q1:(mat==1)?k1:(mat==2)?v1:(mat==3)?q2:(mat==4)?k2:v2;
    dst = base + mat*65536;
  } else if (b < 416){ tb = b-384;  K=128;  N=256;  src=embed_W; dst=base+393216; }
  else if (b < 480){ tb = b-416;  K=256;  N=256;  src=temp_W;  dst=base+425984; }
  else if (b < 736){ tb = b-480;  K=256;  N=1024; src=iW1;     dst=base+491520; }
  else if (b < 992){ tb = b-736;  K=1024; N=256;  src=iW2;     dst=base+753664; }
  else if (b < 1248){ tb = b-992; K=256;  N=1024; src=eW1;     dst=base+1015808; }
  else               { tb = b-1248; K=1024; N=256; src=eW2;    dst=base+1277952; }
  const int nt = N>>5;
  const int N0 = (tb & (nt-1))<<5;
  const int K0 = (tb/nt)<<5;
  {
    int r = tid>>3, c0 = (tid&7)<<2;
    int k = K0+r, n = N0+c0;
    const float* p = qkv ? (src + ((n>>6)<<14) + (k<<6) + (n&63))
                         : (src + (size_t)k*N + n);
    float4 v = *(const float4*)p;
    tile[r][c0]=v.x; tile[r][c0+1]=v.y; tile[r][c0+2]=v.z; tile[r][c0+3]=v.w;
  }
  __syncthreads();
  {
    int r = tid>>3, c0 = (tid&7)<<2;
    f16x4 o;
    o[0]=(h16)tile[c0][r]; o[1]=(h16)tile[c0+1][r];
    o[2]=(h16)tile[c0+2][r]; o[3]=(h16)tile[c0+3][r];
    *(f16x4*)(dst + (size_t)(N0+r)*K + K0 + c0) = o;
  }
}

// ---------------------------------------------------------------- embed + pe + LN0 (fused)
__global__ __launch_bounds__(256) void k_embed(
    const float* __restrict__ x, const h16* __restrict__ Et,
    const float* __restrict__ pe, const float* __restrict__ gate,
    const float* __restrict__ g0, const float* __restrict__ b0,
    float* __restrict__ A){
  __shared__ char pool[65536];
  h16*  As  = (h16*)pool;
  float* res = (float*)pool;
  const int tid = threadIdx.x, lane = tid&63, w = tid>>6;
  const int lr = lane&15, g = lane>>4;
  const int m0 = blockIdx.x<<6;
  #pragma unroll
  for (int it=0; it<8; it++){
    int f4 = it*256 + tid;
    int row = f4>>5, c4 = (f4&31)<<2;
    float4 v = *(const float4*)(x + (size_t)(m0+row)*192 + c4);
    float4 gg = *(const float4*)(gate + (((m0+row)>>6)<<7) + c4);
    v.x*=gg.x; v.y*=gg.y; v.z*=gg.z; v.w*=gg.w;
    int idx = ((row<<7) + c4) ^ ((row&7)<<3);
    f16x4 o; o[0]=(h16)v.x; o[1]=(h16)v.y; o[2]=(h16)v.z; o[3]=(h16)v.w;
    *(f16x4*)&As[idx] = o;
  }
  __syncthreads();
  f32x4 acc[4][4];
  #pragma unroll
  for (int a=0;a<4;a++)
    #pragma unroll
    for (int b=0;b<4;b++) acc[a][b] = (f32x4){0,0,0,0};
  #pragma unroll
  for (int i=0; i<4; i++){
    int kt = (i + w) & 3;
    f16x8 af[4], bf[4];
    #pragma unroll
    for (int rf=0; rf<4; rf++){
      int r = (rf<<4) + lr;
      int idx = ((r<<7) + (kt<<5) + (g<<3)) ^ ((r&7)<<3);
      af[rf] = *(const f16x8*)&As[idx];
    }
    #pragma unroll
    for (int cf=0; cf<4; cf++){
      int n = (w<<6) + (cf<<4) + lr;
      bf[cf] = *(const f16x8*)(Et + (size_t)n*128 + (kt<<5) + (g<<3));
    }
    __builtin_amdgcn_s_setprio(1);
    #pragma unroll
    for (int rf=0; rf<4; rf++)
      #pragma unroll
      for (int cf=0; cf<4; cf++)
        acc[rf][cf] = __builtin_amdgcn_mfma_f32_16x16x32_f16(af[rf], bf[cf], acc[rf][cf], 0,0,0);
    __builtin_amdgcn_s_setprio(0);
  }
  __syncthreads();
  #pragma unroll
  for (int cf=0; cf<4; cf++){
    int col = (w<<6) + (cf<<4) + lr;
    #pragma unroll
    for (int rf=0; rf<4; rf++)
      #pragma unroll
      for (int i=0;i<4;i++){
        int r = (rf<<4) + (g<<2) + i;
        res[(r<<8) + col] = acc[rf][cf][i] + pe[(r<<8) + col];
      }
  }
  __syncthreads();
  {
    float4 gg = *(const float4*)(g0 + (lane<<2));
    float4 bb = *(const float4*)(b0 + (lane<<2));
    for (int rr=0; rr<16; rr++){
      int r = (w<<4) + rr;
      float4 v = *(float4*)&res[(r<<8) + (lane<<2)];
      float sm = wave_sum(v.x+v.y+v.z+v.w);
      float sq = wave_sum(v.x*v.x+v.y*v.y+v.z*v.z+v.w*v.w);
      float mean = sm*(1.f/256.f);
      float rs = rsqrtf(sq*(1.f/256.f) - mean*mean + 1e-10f);
      float4 o;
      o.x=(v.x-mean)*rs*gg.x+bb.x; o.y=(v.y-mean)*rs*gg.y+bb.y;
      o.z=(v.z-mean)*rs*gg.z+bb.z; o.w=(v.w-mean)*rs*gg.w+bb.w;
      *(float4*)(A + (size_t)(m0+r)*256 + (lane<<2)) = o;
    }
  }
}

// ---------------------------------------------------------------- fused intra (r13-verified)
__global__ __launch_bounds__(512,1) void k_intra(
    const float* __restrict__ A, const h16* __restrict__ Wqkv,
    float* __restrict__ Out){
  __shared__ h16 Xs[64*256];
  __shared__ h16 Qs[4*64*64];
  __shared__ h16 Ks[4*64*64];
  __shared__ h16 VsT[4*64*64];
  __shared__ h16 Ps[8*16*64];
  const int tid = threadIdx.x, lane = tid&63, w = tid>>6;
  const int lr = lane&15, g = lane>>4;
  const int m0 = blockIdx.x<<6;
  #pragma unroll
  for (int rr=0; rr<8; rr++){
    int r = (w<<3) + rr;
    float4 v = *(const float4*)(A + (size_t)(m0+r)*256 + (lane<<2));
    f16x4 o; o[0]=(h16)v.x; o[1]=(h16)v.y; o[2]=(h16)v.z; o[3]=(h16)v.w;
    int idx = ((r<<8) + (lane<<2)) ^ ((r&7)<<3);
    *(f16x4*)&Xs[idx] = o;
  }
  __syncthreads();
  f32x4 acc[4][6];
  #pragma unroll
  for (int a=0;a<4;a++)
    #pragma unroll
    for (int b=0;b<6;b++) acc[a][b] = (f32x4){0,0,0,0};
  #pragma unroll
  for (int kt=0; kt<8; kt++){
    f16x8 af[4], bf[6];
    #pragma unroll
    for (int rf=0; rf<4; rf++){
      int r = (rf<<4) + lr;
      int idx = ((r<<8) + (kt<<5) + (g<<3)) ^ ((r&7)<<3);
      af[rf] = *(const f16x8*)&Xs[idx];
    }
    #pragma unroll
    for (int m=0;m<3;m++)
      #pragma unroll
      for (int cf=0;cf<2;cf++){
        int n = (w<<5) + (cf<<4) + lr;
        bf[m*2+cf] = *(const f16x8*)(Wqkv + (size_t)m*65536 + (size_t)n*256 + (kt<<5) + (g<<3));
      }
    __builtin_amdgcn_s_setprio(1);
    #pragma unroll
    for (int rf=0; rf<4; rf++)
      #pragma unroll
      for (int mc=0; mc<6; mc++)
        acc[rf][mc] = __builtin_amdgcn_mfma_f32_16x16x32_f16(af[rf], bf[mc], acc[rf][mc], 0,0,0);
    __builtin_amdgcn_s_setprio(0);
  }
  #pragma unroll
  for (int cf=0; cf<2; cf++){
    int n = (w<<5) + (cf<<4) + lr;
    int head = n>>6, d = n&63;
    int hb = head<<12;
    int vkey = (d + (d>>3)) & 7;
    #pragma unroll
    for (int rf=0; rf<4; rf++)
      #pragma unroll
      for (int i=0;i<4;i++){
        int qrow = (rf<<4) + (g<<2) + i;
        Qs[hb + (qrow<<6) + (((d>>3) ^ (qrow&7))<<3) + (d&7)] = (h16)acc[rf][0*2+cf][i];
        Ks[hb + (qrow<<6) + (((d>>3) ^ (qrow&7))<<3) + (d&7)] = (h16)acc[rf][1*2+cf][i];
        VsT[hb + (d<<6) + (((qrow>>3) ^ vkey)<<3) + (qrow&7)] = (h16)acc[rf][2*2+cf][i];
      }
  }
  __syncthreads();
  #pragma unroll
  for (int sl=0; sl<2; sl++){
    int slot = w + (sl<<3);
    int head = slot>>2, q0 = (slot&3)<<4;
    const int hb = head<<12;
    f16x8 qf[2];
    #pragma unroll
    for (int ks=0; ks<2; ks++)
      qf[ks] = *(const f16x8*)&Qs[hb + ((q0+lr)<<6) + (((g + (ks<<2)) ^ (lr&7))<<3)];
    f32x4 sa[4];
    #pragma unroll
    for (int mm=0;mm<4;mm++) sa[mm] = (f32x4){0,0,0,0};
    __builtin_amdgcn_s_setprio(1);
    #pragma unroll
    for (int ks=0; ks<2; ks++)
      #pragma unroll
      for (int mm=0;mm<4;mm++){
        int krow = (mm<<4) + lr;
        f16x8 af = *(const f16x8*)&Ks[hb + (krow<<6) + (((g + (ks<<2)) ^ (krow&7))<<3)];
        sa[mm] = __builtin_amdgcn_mfma_f32_16x16x32_f16(af, qf[ks], sa[mm], 0,0,0);
      }
    __builtin_amdgcn_s_setprio(0);
    float pmax = -1e30f;
    #pragma unroll
    for (int mm=0;mm<4;mm++)
      #pragma unroll
      for (int i=0;i<4;i++) pmax = fmaxf(pmax, sa[mm][i]);
    pmax = fmaxf(pmax, __shfl_xor(pmax, 16));
    pmax = fmaxf(pmax, __shfl_xor(pmax, 32));
    float ps = 0.f;
    f16x4 pv[4];
    #pragma unroll
    for (int mm=0;mm<4;mm++)
      #pragma unroll
      for (int i=0;i<4;i++){
        float p = __expf(sa[mm][i] - pmax);
        ps += p;
        pv[mm][i] = (h16)p;
      }
    ps += __shfl_xor(ps, 16);
    ps += __shfl_xor(ps, 32);
    const int pbase = w<<10;
    #pragma unroll
    for (int mm=0;mm<4;mm++){
      int k0 = (mm<<4) + (g<<2);
      int unit = k0>>3, off = k0&7;
      *(f16x4*)&Ps[pbase + (lr<<6) + ((unit ^ (lr&7))<<3) + off] = pv[mm];
    }
    f32x4 oc[4];
    #pragma unroll
    for (int cf=0;cf<4;cf++) oc[cf] = (f32x4){0,0,0,0};
    __builtin_amdgcn_s_setprio(1);
    #pragma unroll
    for (int ks=0; ks<2; ks++){
      f16x8 pa = *(const f16x8*)&Ps[pbase + (lr<<6) + (((g + (ks<<2)) ^ (lr&7))<<3)];
      #pragma unroll
      for (int cf=0;cf<4;cf++){
        int d = (cf<<4) + lr;
        int key = (d + (d>>3)) & 7;
        f16x8 bf = *(const f16x8*)&VsT[hb + (d<<6) + (((g + (ks<<2)) ^ key)<<3)];
        oc[cf] = __builtin_amdgcn_mfma_f32_16x16x32_f16(pa, bf, oc[cf], 0,0,0);
      }
    }
    __builtin_amdgcn_s_setprio(0);
    float linv = 1.0f/(ps*8.0f);
    #pragma unroll
    for (int i=0;i<4;i++){
      float li = __shfl(linv, (g<<4) + (g<<2) + i);
      int row = m0 + q0 + (g<<2) + i;
      #pragma unroll
      for (int cf=0;cf<4;cf++){
        int col = (head<<6) + (cf<<4) + lr;
        size_t ga = (size_t)row*256 + col;
        Out[ga] = oc[cf][i]*li + A[ga];
      }
    }
  }
}

// ---------------------------------------------------------------- fused QKV projection (inter)
template<bool DOLN>
__global__ __launch_bounds__(512) void k_qkv(
    const float* __restrict__ X,
    const float* __restrict__ lng, const float* __restrict__ lnb,
    const h16* __restrict__ Bt0,
    h16* __restrict__ Qh, h16* __restrict__ Kh, h16* __restrict__ Vh){
  __shared__ h16 Xs[64*256];
  const int tid = threadIdx.x, lane = tid&63, w = tid>>6;
  const int lr = lane&15, g = lane>>4;
  const int m0 = blockIdx.x<<6;
  {
    float4 gg, bb;
    if (DOLN){ gg = *(const float4*)(lng + (lane<<2)); bb = *(const float4*)(lnb + (lane<<2)); }
    #pragma unroll
    for (int rr=0; rr<8; rr++){
      int r = (w<<3) + rr;
      float4 v = *(const float4*)(X + (size_t)(m0+r)*256 + (lane<<2));
      if (DOLN){
        float sm = wave_sum(v.x+v.y+v.z+v.w);
        float sq = wave_sum(v.x*v.x+v.y*v.y+v.z*v.z+v.w*v.w);
        float mean = sm*(1.f/256.f);
        float rs = rsqrtf(sq*(1.f/256.f) - mean*mean + 1e-10f);
        v.x=(v.x-mean)*rs*gg.x+bb.x; v.y=(v.y-mean)*rs*gg.y+bb.y;
        v.z=(v.z-mean)*rs*gg.z+bb.z; v.w=(v.w-mean)*rs*gg.w+bb.w;
      }
      f16x4 o; o[0]=(h16)v.x; o[1]=(h16)v.y; o[2]=(h16)v.z; o[3]=(h16)v.w;
      int idx = ((r<<8) + (lane<<2)) ^ ((r&7)<<3);
      *(f16x4*)&Xs[idx] = o;
    }
  }
  __syncthreads();
  f32x4 acc[4][3];
  #pragma unroll
  for (int a=0;a<4;a++)
    #pragma unroll
    for (int m=0;m<3;m++) acc[a][m] = (f32x4){0,0,0,0};
  #pragma unroll
  for (int i=0; i<8; i++){
    int kt = (i + w) & 7;
    f16x8 af[4], bf[3];
    #pragma unroll
    for (int rf=0; rf<4; rf++){
      int r = (rf<<4) + lr;
      int idx = ((r<<8) + (kt<<5) + (g<<3)) ^ ((r&7)<<3);
      af[rf] = *(const f16x8*)&Xs[idx];
    }
    #pragma unroll
    for (int m=0;m<3;m++){
      int n = (w<<4) + lr;
      bf[m] = *(const f16x8*)(Bt0 + (size_t)m*65536 + (size_t)n*256 + (kt<<5) + (g<<3));
    }
    __builtin_amdgcn_s_setprio(1);
    #pragma unroll
    for (int rf=0; rf<4; rf++)
      #pragma unroll
      for (int m=0;m<3;m++)
        acc[rf][m] = __builtin_amdgcn_mfma_f32_16x16x32_f16(af[rf], bf[m], acc[rf][m], 0,0,0);
    __builtin_amdgcn_s_setprio(0);
  }
  const int col = (w<<4) + lr;
  #pragma unroll
  for (int m=0;m<3;m++){
    h16* dst = (m==0)?Qh:(m==1)?Kh:Vh;
    #pragma unroll
    for (int rf=0; rf<4; rf++)
      #pragma unroll
      for (int i=0;i<4;i++){
        int r = m0 + (rf<<4) + (g<<2) + i;
        dst[(size_t)r*128 + col] = (h16)acc[rf][m][i];
      }
  }
}

// ---------------------------------------------------------------- MFMA attention (inter, r10-verified)
template<int NT, int QG>
__global__ __launch_bounds__(256) void k_attn16(
    const h16* __restrict__ Qh, const h16* __restrict__ Kh, const h16* __restrict__ Vh,
    const float* __restrict__ Resid, float* __restrict__ Out, int hbase){
  __shared__ h16 Ks[64*64];
  __shared__ h16 VsT[64*64];
  __shared__ h16 Ps[4*QG*16*64];
  const int tid = threadIdx.x, lane = tid&63, w = tid>>6;
  const int lr = lane&15, g = lane>>4;
  int hh, t=0, qc=0, s=0;
  if (NT==1){ s = blockIdx.x; hh = blockIdx.y; }
  else      { hh = blockIdx.x; t = blockIdx.y; qc = blockIdx.z; }
  const int ccol = hh<<6;
  const int gcol = (hbase+hh)<<6;

  f16x8 qf[QG][2];
  #pragma unroll
  for (int grp=0; grp<QG; grp++){
    int ql = grp*64 + (w<<4) + lr;
    size_t m = (NT==1) ? ((size_t)s*64 + ql) : (((size_t)qc*(64*QG) + ql)*64 + t);
    const h16* qp = Qh + m*128 + ccol + (g<<3);
    qf[grp][0] = *(const f16x8*)qp;
    qf[grp][1] = *(const f16x8*)(qp + 32);
  }

  f32x4 oc[QG][4];
  float m_r[QG], l_r[QG];
  #pragma unroll
  for (int grp=0; grp<QG; grp++){
    #pragma unroll
    for (int cf=0;cf<4;cf++) oc[grp][cf] = (f32x4){0,0,0,0};
    m_r[grp] = -1e30f; l_r[grp] = 0.f;
  }

  for (int kb=0; kb<NT; kb++){
    __syncthreads();
    #pragma unroll
    for (int it=0; it<2; it++){
      int u = it*256 + tid;
      int row = u>>3, un = u&7;
      size_t m = (NT==1) ? ((size_t)s*64 + row) : (((size_t)kb*64 + row)*64 + t);
      f16x8 kv = *(const f16x8*)(Kh + m*128 + ccol + (un<<3));
      *(f16x8*)&Ks[(row<<6) + ((un ^ (row&7))<<3)] = kv;
      f16x8 vv = *(const f16x8*)(Vh + m*128 + ccol + (un<<3));
      #pragma unroll
      for (int j=0;j<8;j++){
        int d = (un<<3) + j;
        int key = (d + un) & 7;
        VsT[(d<<6) + ((((row>>3) ^ key))<<3) + (row&7)] = vv[j];
      }
    }
    __syncthreads();
    #pragma unroll
    for (int grp=0; grp<QG; grp++){
      f32x4 sa[4];
      #pragma unroll
      for (int mm=0;mm<4;mm++) sa[mm] = (f32x4){0,0,0,0};
      __builtin_amdgcn_s_setprio(1);
      #pragma unroll
      for (int ks=0; ks<2; ks++){
        #pragma unroll
        for (int mm=0;mm<4;mm++){
          int krow = (mm<<4) + lr;
          f16x8 af = *(const f16x8*)&Ks[(krow<<6) + (((g + (ks<<2)) ^ (krow&7))<<3)];
          sa[mm] = __builtin_amdgcn_mfma_f32_16x16x32_f16(af, qf[grp][ks], sa[mm], 0,0,0);
        }
      }
      __builtin_amdgcn_s_setprio(0);
      float pmax = -1e30f;
      #pragma unroll
      for (int mm=0;mm<4;mm++)
        #pragma unroll
        for (int i=0;i<4;i++) pmax = fmaxf(pmax, sa[mm][i]);
      pmax = fmaxf(pmax, __shfl_xor(pmax, 16));
      pmax = fmaxf(pmax, __shfl_xor(pmax, 32));
      float mn = fmaxf(m_r[grp], pmax);
      float sca = __expf(m_r[grp] - mn);
      m_r[grp] = mn;
      float ps = 0.f;
      f16x4 pv[4];
      #pragma unroll
      for (int mm=0;mm<4;mm++){
        #pragma unroll
        for (int i=0;i<4;i++){
          float p = __expf(sa[mm][i] - mn);
          ps += p;
          pv[mm][i] = (h16)p;
        }
      }
      ps += __shfl_xor(ps, 16);
      ps += __shfl_xor(ps, 32);
      l_r[grp] = l_r[grp]*sca + ps;
      const int pbase = ((w*QG + grp)<<10);
      #pragma unroll
      for (int mm=0;mm<4;mm++){
        int k0 = (mm<<4) + (g<<2);
        int unit = k0>>3, off = k0&7;
        *(f16x4*)&Ps[pbase + (lr<<6) + ((unit ^ (lr&7))<<3) + off] = pv[mm];
      }
      #pragma unroll
      for (int i=0;i<4;i++){
        float si = __shfl(sca, (g<<4) + (g<<2) + i);
        #pragma unroll
        for (int cf=0;cf<4;cf++) oc[grp][cf][i] *= si;
      }
      __builtin_amdgcn_s_setprio(1);
      #pragma unroll
      for (int ks=0; ks<2; ks++){
        f16x8 pa = *(const f16x8*)&Ps[pbase + (lr<<6) + (((g + (ks<<2)) ^ (lr&7))<<3)];
        #pragma unroll
        for (int cf=0;cf<4;cf++){
          int d = (cf<<4) + lr;
          int key = (d + (d>>3)) & 7;
          f16x8 bf = *(const f16x8*)&VsT[(d<<6) + (((g + (ks<<2)) ^ key)<<3)];
          oc[grp][cf] = __builtin_amdgcn_mfma_f32_16x16x32_f16(pa, bf, oc[grp][cf], 0,0,0);
        }
      }
      __builtin_amdgcn_s_setprio(0);
    }
  }
  #pragma unroll
  for (int grp=0; grp<QG; grp++){
    float linv = 1.0f/(l_r[grp]*8.0f);
    #pragma unroll
    for (int i=0;i<4;i++){
      float li = __shfl(linv, (g<<4) + (g<<2) + i);
      int ql = grp*64 + (w<<4) + (g<<2) + i;
      size_t m = (NT==1) ? ((size_t)s*64 + ql) : (((size_t)qc*(64*QG) + ql)*64 + t);
      #pragma unroll
      for (int cf=0;cf<4;cf++){
        int d = (cf<<4) + lr;
        size_t ga = m*256 + gcol + d;
        Out[ga] = oc[grp][cf][i]*li + Resid[ga];
      }
    }
  }
}

// ---------------------------------------------------------------- LN -> f16 buffer
__global__ __launch_bounds__(256) void k_lnh(const float* __restrict__ in,
    const float* __restrict__ g, const float* __restrict__ b,
    h16* __restrict__ out){
  const int wv = threadIdx.x>>6, lane = threadIdx.x&63;
  const size_t row = (size_t)blockIdx.x*4 + wv;
  float4 v = *(const float4*)(in + row*256 + (lane<<2));
  float sm = wave_sum(v.x+v.y+v.z+v.w);
  float sq = wave_sum(v.x*v.x+v.y*v.y+v.z*v.z+v.w*v.w);
  float mean = sm*(1.f/256.f);
  float rs = rsqrtf(sq*(1.f/256.f) - mean*mean + 1e-10f);
  float4 gg = *(const float4*)(g + (lane<<2));
  float4 bb = *(const float4*)(b + (lane<<2));
  f16x4 o;
  o[0]=(h16)((v.x-mean)*rs*gg.x+bb.x); o[1]=(h16)((v.y-mean)*rs*gg.y+bb.y);
  o[2]=(h16)((v.z-mean)*rs*gg.z+bb.z); o[3]=(h16)((v.w-mean)*rs*gg.w+bb.w);
  *(f16x4*)(out + row*256 + (lane<<2)) = o;
}

// ---------------------------------------------------------------- MFMA FFN v7 — LDS-resident weight chunks
// grid 256, 512 thr, 256 rows/block. 8 hidden chunks of 128:
// stage W1c[128n][256k] 64K + W2c[256n][128k] 64K once; 4 row-tiles of 64:
// Pool (32K) = Xs [64][256] during GEMM1, Hc [64][128] during GEMM2.
// Zero global loads inside MFMA loops. acc2[rt] persists across chunks.
__global__ __launch_bounds__(512,1) void k_ffn7(
    const h16* __restrict__ Xh, const float* __restrict__ Resid,
    float* __restrict__ Out,
    const h16* __restrict__ W1t, const float* __restrict__ b1,
    const h16* __restrict__ W2t, const float* __restrict__ b2){
  __shared__ h16 W1c[128*256];
  __shared__ h16 W2c[256*128];
  __shared__ h16 Pool[64*256];
  const int tid = threadIdx.x, lane = tid&63, w = tid>>6;
  const int lr = lane&15, g = lane>>4;
  const size_t R0 = (size_t)blockIdx.x<<8;

  float b2v[2];
  b2v[0] = b2[(w<<5)+lr]; b2v[1] = b2[(w<<5)+16+lr];

  f32x4 acc2[4][4][2];
  #pragma unroll
  for (int rt=0;rt<4;rt++)
    #pragma unroll
    for (int rf=0;rf<4;rf++){
      acc2[rt][rf][0]=(f32x4){0,0,0,0}; acc2[rt][rf][1]=(f32x4){0,0,0,0};
    }

  for (int hc=0; hc<8; hc++){
    __syncthreads();   // prior GEMM2 reads of W2c/Pool complete
    // stage W1c: thread: n_loc = tid>>2 (0..127), part = tid&3 -> units part*8..+7
    {
      int n1 = tid>>2, p1 = tid&3;
      const h16* s1 = W1t + (size_t)((hc<<7) + n1)*256;
      #pragma unroll
      for (int j=0;j<8;j++){
        int u = (p1<<3)+j;
        *(f16x8*)&W1c[(n1<<8) + ((u ^ (n1&7))<<3)] = *(const f16x8*)(s1 + (u<<3));
      }
      int n2 = tid>>1, p2 = tid&1;
      const h16* s2 = W2t + (size_t)n2*1024 + (hc<<7);
      #pragma unroll
      for (int j=0;j<8;j++){
        int u = (p2<<3)+j;
        *(f16x8*)&W2c[(n2<<7) + ((u ^ (n2&7))<<3)] = *(const f16x8*)(s2 + (u<<3));
      }
    }
    float b1v = b1[(hc<<7) + (w<<4) + lr];

    #pragma unroll
    for (int rt=0; rt<4; rt++){
      __syncthreads();  // W staged (rt=0) / prior GEMM2 Pool reads done
      // stage Xs [64][256] f16 (swizzle key row&7 on 16B units)
      {
        const h16* xsrc = Xh + (R0 + (rt<<6))*256;
        #pragma unroll
        for (int it=0; it<4; it++){
          int e = it*512 + tid;
          int row = e>>5, u = e&31;
          *(f16x8*)&Pool[(row<<8) + ((u ^ (row&7))<<3)] =
              *(const f16x8*)(xsrc + (row<<8) + (u<<3));
        }
      }
      __syncthreads();
      // GEMM1: n = w*16+lr (chunk-local), K=256
      f32x4 acc1[4];
      #pragma unroll
      for (int rf=0;rf<4;rf++) acc1[rf] = (f32x4){0,0,0,0};
      const int n1 = (w<<4) + lr;
      #pragma unroll
      for (int kt=0; kt<8; kt++){
        f16x8 af[4];
        #pragma unroll
        for (int rf=0; rf<4; rf++){
          int r = (rf<<4) + lr;
          af[rf] = *(const f16x8*)&Pool[((r<<8) + (kt<<5) + (g<<3)) ^ ((r&7)<<3)];
        }
        f16x8 bf = *(const f16x8*)&W1c[(n1<<8) + ((((kt<<2)+g) ^ (n1&7))<<3)];
        __builtin_amdgcn_s_setprio(1);
        #pragma unroll
        for (int rf=0; rf<4; rf++)
          acc1[rf] = __builtin_amdgcn_mfma_f32_16x16x32_f16(af[rf], bf, acc1[rf], 0,0,0);
        __builtin_amdgcn_s_setprio(0);
      }
      __syncthreads();  // all Xs reads done -> Pool becomes Hc
      // relu+bias -> Hc [64][128] (rows 256B, key row&7)
      #pragma unroll
      for (int rf=0; rf<4; rf++)
        #pragma unroll
        for (int i=0;i<4;i++){
          int r = (rf<<4) + (g<<2) + i;
          float hv = fmaxf(acc1[rf][i] + b1v, 0.f);
          Pool[((r<<7) + n1) ^ ((r&7)<<3)] = (h16)hv;
        }
      __syncthreads();
      // GEMM2: out cols (w<<5)+(cf<<4)+lr, K=128 (4 kt)
      #pragma unroll
      for (int kt=0; kt<4; kt++){
        f16x8 af[4], bf[2];
        #pragma unroll
        for (int rf=0; rf<4; rf++){
          int r = (rf<<4) + lr;
          af[rf] = *(const f16x8*)&Pool[((r<<7) + (kt<<5) + (g<<3)) ^ ((r&7)<<3)];
        }
        #pragma unroll
        for (int cf=0; cf<2; cf++){
          int n = (w<<5) + (cf<<4) + lr;
          bf[cf] = *(const f16x8*)&W2c[(n<<7) + ((((kt<<2)+g) ^ (n&7))<<3)];
        }
        __builtin_amdgcn_s_setprio(1);
        #pragma unroll
        for (int rf=0; rf<4; rf++)
          #pragma unroll
          for (int cf=0; cf<2; cf++)
            acc2[rt][rf][cf] = __builtin_amdgcn_mfma_f32_16x16x32_f16(
                af[rf], bf[cf], acc2[rt][rf][cf], 0,0,0);
        __builtin_amdgcn_s_setprio(0);
      }
    }
  }
  // epilogue: + b2 + residual
  #pragma unroll
  for (int rt=0; rt<4; rt++)
    #pragma unroll
    for (int cf=0; cf<2; cf++){
      int col = (w<<5) + (cf<<4) + lr;
      #pragma unroll
      for (int rf=0; rf<4; rf++)
        #pragma unroll
        for (int i=0;i<4;i++){
          size_t r = R0 + (rt<<6) + (rf<<4) + (g<<2) + i;
          Out[r*256 + col] = acc2[rt][rf][cf][i] + b2v[cf] + Resid[r*256 + col];
        }
    }
}

// ---------------------------------------------------------------- fused head (r13-verified)
__global__ __launch_bounds__(256) void k_head(
    const float* __restrict__ Bb, const h16* __restrict__ Tt,
    const float* __restrict__ predW, const float* __restrict__ predb,
    float* __restrict__ out){
  __shared__ h16 Xs[64*256];
  __shared__ float X1s[64*256];
  __shared__ float lam[64];
  __shared__ float red[4];
  const int tid = threadIdx.x, lane = tid&63, w = tid>>6;
  const int lr = lane&15, g = lane>>4;
  const size_t m0 = (size_t)blockIdx.x<<6;
  #pragma unroll
  for (int it=0; it<16; it++){
    int f4 = it*256 + tid;
    int row = f4>>6, c4 = (f4&63)<<2;
    float4 v = *(const float4*)(Bb + (m0+row)*256 + c4);
    int idx = ((row<<8) + c4) ^ ((row&7)<<3);
    f16x4 o; o[0]=(h16)v.x; o[1]=(h16)v.y; o[2]=(h16)v.z; o[3]=(h16)v.w;
    *(f16x4*)&Xs[idx] = o;
  }
  __syncthreads();
  f32x4 acc[4][4];
  #pragma unroll
  for (int rf=0;rf<4;rf++)
    #pragma unroll
    for (int cf=0;cf<4;cf++) acc[rf][cf] = (f32x4){0,0,0,0};
  #pragma unroll
  for (int kt=0; kt<8; kt++){
    f16x8 af[4], bf[4];
    #pragma unroll
    for (int rf=0; rf<4; rf++){
      int r = (rf<<4) + lr;
      int idx = ((r<<8) + (kt<<5) + (g<<3)) ^ ((r&7)<<3);
      af[rf] = *(const f16x8*)&Xs[idx];
    }
    #pragma unroll
    for (int cf=0; cf<4; cf++){
      int n = (w<<6) + (cf<<4) + lr;
      bf[cf] = *(const f16x8*)(Tt + (size_t)n*256 + (kt<<5) + (g<<3));
    }
    __builtin_amdgcn_s_setprio(1);
    #pragma unroll
    for (int rf=0; rf<4; rf++)
      #pragma unroll
      for (int cf=0; cf<4; cf++)
        acc[rf][cf] = __builtin_amdgcn_mfma_f32_16x16x32_f16(af[rf], bf[cf], acc[rf][cf], 0,0,0);
    __builtin_amdgcn_s_setprio(0);
  }
  #pragma unroll
  for (int cf=0; cf<4; cf++){
    int col = (w<<6) + (cf<<4) + lr;
    #pragma unroll
    for (int rf=0; rf<4; rf++)
      #pragma unroll
      for (int i=0;i<4;i++){
        int r = (rf<<4) + (g<<2) + i;
        X1s[(r<<8) + col] = acc[rf][cf][i];
      }
  }
  __syncthreads();
  float lg[16];
  for (int r=0;r<16;r++){
    int trow = (w<<4) + r;
    float4 xa = *(float4*)&X1s[(trow<<8) + (lane<<2)];
    float4 xc = *(float4*)&X1s[(63<<8) + (lane<<2)];
    lg[r] = wave_sum(xa.x*xc.x + xa.y*xc.y + xa.z*xc.z + xa.w*xc.w);
  }
  if (lane==0){
    #pragma unroll
    for (int r=0;r<16;r++) lam[(w<<4)+r] = lg[r];
  }
  __syncthreads();
  if (tid < 64){
    float v = lam[tid];
    float mx = wave_max(v);
    float p = __expf(v-mx);
    float sm = wave_sum(p);
    lam[tid] = p/sm;
  }
  __syncthreads();
  float ag = 0.f;
  for (int t=0;t<64;t++)
    ag += lam[t]*(float)Xs[((t<<8)+tid) ^ ((t&7)<<3)];
  float wsum = wave_sum(ag * predW[tid]);
  if (lane==0) red[w] = wsum;
  __syncthreads();
  if (tid==0) out[blockIdx.x] = red[0]+red[1]+red[2]+red[3] + predb[0];
}

// ================================================================ launch
extern "C" void kernel_launch(void* const* d_in, const int* in_sizes, int n_in,
                              void* d_out, int out_size, void* d_ws, size_t ws_size,
                              hipStream_t stream){
  const float* x       = (const float*)d_in[0];
  const float* gate_W  = (const float*)d_in[1];
  const float* gate_b  = (const float*)d_in[2];
  const float* embed_W = (const float*)d_in[3];
  const float* ln0_g   = (const float*)d_in[4];
  const float* ln0_b   = (const float*)d_in[5];
  const float* iln_g   = (const float*)d_in[9];
  const float* iln_b   = (const float*)d_in[10];
  const float* iW1     = (const float*)d_in[11];
  const float* ib1     = (const float*)d_in[12];
  const float* iW2     = (const float*)d_in[13];
  const float* ib2     = (const float*)d_in[14];
  const float* eln1_g  = (const float*)d_in[18];
  const float* eln1_b  = (const float*)d_in[19];
  const float* eln2_g  = (const float*)d_in[20];
  const float* eln2_b  = (const float*)d_in[21];
  const float* eW1     = (const float*)d_in[22];
  const float* eb1     = (const float*)d_in[23];
  const float* eW2     = (const float*)d_in[24];
  const float* eb2     = (const float*)d_in[25];
  const float* temp_W  = (const float*)d_in[26];
  const float* pred_W  = (const float*)d_in[27];
  const float* pred_b  = (const float*)d_in[28];
  float* out = (float*)d_out;

  float* pe    = (float*)d_ws;
  float* gate  = pe + 16384;
  h16* fQKV = (h16*)((char*)d_ws + ((size_t)4<<20));
  h16* fE   = fQKV + 393216;
  h16* fT   = fE + 32768;
  h16* fW1i = fT + 65536;
  h16* fW2i = fW1i + 262144;
  h16* fW1e = fW2i + 262144;
  h16* fW2e = fW1e + 262144;
  const size_t MR = (size_t)65536*256, MH = (size_t)65536*128;
  float* A  = (float*)((char*)d_ws + ((size_t)8<<20));
  float* Bb = A + MR;
  h16* Qh = (h16*)(Bb + MR);
  h16* Kh = Qh + MH;
  h16* Vh = Kh + MH;
  h16* Xh = (h16*)A;   // A is dead after k_intra; reuse as LN'd f16 buffer

  k_pe  <<<64,  256, 0, stream>>>(pe);
  k_gate<<<1024, 64, 0, stream>>>(x, gate_W, gate_b, gate);
  k_t16all<<<1504,256,0,stream>>>(
      (const float*)d_in[6],(const float*)d_in[7],(const float*)d_in[8],
      (const float*)d_in[15],(const float*)d_in[16],(const float*)d_in[17],
      embed_W, temp_W, iW1, iW2, eW1, eW2, fQKV);

  // A = LN0(gate*x @ embed_W + pe)
  k_embed<<<1024,256,0,stream>>>(x, fE, pe, gate, ln0_g, ln0_b, A);

  // fused intra QKV+attention: r -> Bb
  k_intra<<<1024,512,0,stream>>>(A, fQKV, Bb);
  k_lnh<<<16384,256,0,stream>>>(Bb, iln_g, iln_b, Xh);
  k_ffn7<<<256,512,0,stream>>>(Xh, Bb, Bb, fW1i, ib1, fW2i, ib2);

  // inter attention (transposed batching), LN1 fused into QKV; r2 -> Bb
  for (int hp=0; hp<2; hp++){
    int hb = hp*2;
    k_qkv<true><<<1024,512,0,stream>>>(Bb, eln1_g, eln1_b,
        fQKV + 3*65536 + hb*16384, Qh, Kh, Vh);
    k_attn16<16,1><<<dim3(2,64,16),256,0,stream>>>(Qh, Kh, Vh, Bb, Bb, hb);
  }
  k_lnh<<<16384,256,0,stream>>>(Bb, eln2_g, eln2_b, Xh);
  k_ffn7<<<256,512,0,stream>>>(Xh, Bb, Bb, fW1e, eb1, fW2e, eb2);

  // fused head
  k_head<<<1024,256,0,stream>>>(Bb, fT, pred_W, pred_b, out);
}

// Round 15
// 718.186 us; speedup vs baseline: 1.2099x; 1.2099x over previous
//
#include <hip/hip_runtime.h>

// S=1024, T=64, F=128, J=64, E=256, H=4, DH=64. M = S*T = 65536 rows.
// r15: swapped-operand MFMA C-layouts -> vectorized (f16x4) scatters in
// k_ffn5 relu, k_intra QKV scatter, k_qkv global stores. Rest = r13 (723us).

typedef _Float16 h16;
typedef __attribute__((ext_vector_type(8))) _Float16 f16x8;
typedef __attribute__((ext_vector_type(4))) _Float16 f16x4;
typedef __attribute__((ext_vector_type(4))) float f32x4;

__device__ inline float wave_sum(float v){
  #pragma unroll
  for (int o=32;o;o>>=1) v += __shfl_xor(v,o);
  return v;
}
__device__ inline float wave_max(float v){
  #pragma unroll
  for (int o=32;o;o>>=1) v = fmaxf(v,__shfl_xor(v,o));
  return v;
}

// ---------------------------------------------------------------- pe table
__global__ __launch_bounds__(256) void k_pe(float* __restrict__ pe){
  int t = blockIdx.x, i = threadIdx.x;
  float two_i = (float)((i>>1)<<1);
  float dv = powf(100004.0f, two_i*(1.0f/256.0f));
  float v = (float)t / dv;
  pe[t*256+i] = (i&1) ? cosf(v) : sinf(v);
}

// ---------------------------------------------------------------- gate softmax
__global__ __launch_bounds__(64) void k_gate(const float* __restrict__ x,
    const float* __restrict__ gW, const float* __restrict__ gb,
    float* __restrict__ gate){
  int s = blockIdx.x, lane = threadIdx.x;
  __shared__ float xg[64];
  xg[lane] = x[((size_t)s*64+63)*192 + 128 + lane];
  __syncthreads();
  float a0 = gb[lane], a1 = gb[64+lane];
  #pragma unroll 4
  for (int j=0;j<64;j++){
    float xv = xg[j];
    a0 += xv*gW[j*128+lane];
    a1 += xv*gW[j*128+64+lane];
  }
  float mx = wave_max(fmaxf(a0,a1));
  float e0 = __expf(a0-mx), e1 = __expf(a1-mx);
  float sm = wave_sum(e0+e1);
  gate[s*128+lane]    = e0/sm;
  gate[s*128+64+lane] = e1/sm;
}

// ---------------------------------------------------------------- all weight transposes -> f16 [n][k]
__global__ __launch_bounds__(256) void k_t16all(
    const float* __restrict__ q1, const float* __restrict__ k1, const float* __restrict__ v1,
    const float* __restrict__ q2, const float* __restrict__ k2, const float* __restrict__ v2,
    const float* __restrict__ embed_W, const float* __restrict__ temp_W,
    const float* __restrict__ iW1, const float* __restrict__ iW2,
    const float* __restrict__ eW1, const float* __restrict__ eW2,
    h16* __restrict__ base){
  __shared__ float tile[32][33];
  const int b = blockIdx.x, tid = threadIdx.x;
  const float* src; h16* dst; int K, N, tb; bool qkv = false;
  if (b < 384){
    int mat = b>>6; tb = b&63; qkv = true; K = 256; N = 256;
    src = (mat==0)?q1:(mat==1)?k1:(mat==2)?v1:(mat==3)?q2:(mat==4)?k2:v2;
    dst = base + mat*65536;
  } else if (b < 416){ tb = b-384;  K=128;  N=256;  src=embed_W; dst=base+393216; }
  else if (b < 480){ tb = b-416;  K=256;  N=256;  src=temp_W;  dst=base+425984; }
  else if (b < 736){ tb = b-480;  K=256;  N=1024; src=iW1;     dst=base+491520; }
  else if (b < 992){ tb = b-736;  K=1024; N=256;  src=iW2;     dst=base+753664; }
  else if (b < 1248){ tb = b-992; K=256;  N=1024; src=eW1;     dst=base+1015808; }
  else               { tb = b-1248; K=1024; N=256; src=eW2;    dst=base+1277952; }
  const int nt = N>>5;
  const int N0 = (tb & (nt-1))<<5;
  const int K0 = (tb/nt)<<5;
  {
    int r = tid>>3, c0 = (tid&7)<<2;
    int k = K0+r, n = N0+c0;
    const float* p = qkv ? (src + ((n>>6)<<14) + (k<<6) + (n&63))
                         : (src + (size_t)k*N + n);
    float4 v = *(const float4*)p;
    tile[r][c0]=v.x; tile[r][c0+1]=v.y; tile[r][c0+2]=v.z; tile[r][c0+3]=v.w;
  }
  __syncthreads();
  {
    int r = tid>>3, c0 = (tid&7)<<2;
    f16x4 o;
    o[0]=(h16)tile[c0][r]; o[1]=(h16)tile[c0+1][r];
    o[2]=(h16)tile[c0+2][r]; o[3]=(h16)tile[c0+3][r];
    *(f16x4*)(dst + (size_t)(N0+r)*K + K0 + c0) = o;
  }
}

// ---------------------------------------------------------------- embed + pe + LN0 (fused)
__global__ __launch_bounds__(256) void k_embed(
    const float* __restrict__ x, const h16* __restrict__ Et,
    const float* __restrict__ pe, const float* __restrict__ gate,
    const float* __restrict__ g0, const float* __restrict__ b0,
    float* __restrict__ A){
  __shared__ char pool[65536];
  h16*  As  = (h16*)pool;
  float* res = (float*)pool;
  const int tid = threadIdx.x, lane = tid&63, w = tid>>6;
  const int lr = lane&15, g = lane>>4;
  const int m0 = blockIdx.x<<6;
  #pragma unroll
  for (int it=0; it<8; it++){
    int f4 = it*256 + tid;
    int row = f4>>5, c4 = (f4&31)<<2;
    float4 v = *(const float4*)(x + (size_t)(m0+row)*192 + c4);
    float4 gg = *(const float4*)(gate + (((m0+row)>>6)<<7) + c4);
    v.x*=gg.x; v.y*=gg.y; v.z*=gg.z; v.w*=gg.w;
    int idx = ((row<<7) + c4) ^ ((row&7)<<3);
    f16x4 o; o[0]=(h16)v.x; o[1]=(h16)v.y; o[2]=(h16)v.z; o[3]=(h16)v.w;
    *(f16x4*)&As[idx] = o;
  }
  __syncthreads();
  f32x4 acc[4][4];
  #pragma unroll
  for (int a=0;a<4;a++)
    #pragma unroll
    for (int b=0;b<4;b++) acc[a][b] = (f32x4){0,0,0,0};
  #pragma unroll
  for (int i=0; i<4; i++){
    int kt = (i + w) & 3;
    f16x8 af[4], bf[4];
    #pragma unroll
    for (int rf=0; rf<4; rf++){
      int r = (rf<<4) + lr;
      int idx = ((r<<7) + (kt<<5) + (g<<3)) ^ ((r&7)<<3);
      af[rf] = *(const f16x8*)&As[idx];
    }
    #pragma unroll
    for (int cf=0; cf<4; cf++){
      int n = (w<<6) + (cf<<4) + lr;
      bf[cf] = *(const f16x8*)(Et + (size_t)n*128 + (kt<<5) + (g<<3));
    }
    __builtin_amdgcn_s_setprio(1);
    #pragma unroll
    for (int rf=0; rf<4; rf++)
      #pragma unroll
      for (int cf=0; cf<4; cf++)
        acc[rf][cf] = __builtin_amdgcn_mfma_f32_16x16x32_f16(af[rf], bf[cf], acc[rf][cf], 0,0,0);
    __builtin_amdgcn_s_setprio(0);
  }
  __syncthreads();
  #pragma unroll
  for (int cf=0; cf<4; cf++){
    int col = (w<<6) + (cf<<4) + lr;
    #pragma unroll
    for (int rf=0; rf<4; rf++)
      #pragma unroll
      for (int i=0;i<4;i++){
        int r = (rf<<4) + (g<<2) + i;
        res[(r<<8) + col] = acc[rf][cf][i] + pe[(r<<8) + col];
      }
  }
  __syncthreads();
  {
    float4 gg = *(const float4*)(g0 + (lane<<2));
    float4 bb = *(const float4*)(b0 + (lane<<2));
    for (int rr=0; rr<16; rr++){
      int r = (w<<4) + rr;
      float4 v = *(float4*)&res[(r<<8) + (lane<<2)];
      float sm = wave_sum(v.x+v.y+v.z+v.w);
      float sq = wave_sum(v.x*v.x+v.y*v.y+v.z*v.z+v.w*v.w);
      float mean = sm*(1.f/256.f);
      float rs = rsqrtf(sq*(1.f/256.f) - mean*mean + 1e-10f);
      float4 o;
      o.x=(v.x-mean)*rs*gg.x+bb.x; o.y=(v.y-mean)*rs*gg.y+bb.y;
      o.z=(v.z-mean)*rs*gg.z+bb.z; o.w=(v.w-mean)*rs*gg.w+bb.w;
      *(float4*)(A + (size_t)(m0+r)*256 + (lane<<2)) = o;
    }
  }
}

// ---------------------------------------------------------------- fused intra: vectorized scatter (r15)
// Q/K swapped-operand (4 consecutive d per thread), V natural (4 consecutive q).
__global__ __launch_bounds__(512,1) void k_intra(
    const float* __restrict__ A, const h16* __restrict__ Wqkv,
    float* __restrict__ Out){
  __shared__ h16 Xs[64*256];
  __shared__ h16 Qs[4*64*64];
  __shared__ h16 Ks[4*64*64];
  __shared__ h16 VsT[4*64*64];
  __shared__ h16 Ps[8*16*64];
  const int tid = threadIdx.x, lane = tid&63, w = tid>>6;
  const int lr = lane&15, g = lane>>4;
  const int m0 = blockIdx.x<<6;
  #pragma unroll
  for (int rr=0; rr<8; rr++){
    int r = (w<<3) + rr;
    float4 v = *(const float4*)(A + (size_t)(m0+r)*256 + (lane<<2));
    f16x4 o; o[0]=(h16)v.x; o[1]=(h16)v.y; o[2]=(h16)v.z; o[3]=(h16)v.w;
    int idx = ((r<<8) + (lane<<2)) ^ ((r&7)<<3);
    *(f16x4*)&Xs[idx] = o;
  }
  __syncthreads();

  f32x4 aqk[2][2][4];  // [Q/K][cf][mf] swapped: row=n-local, col=q
  f32x4 av[4][2];      // [rf][cf] natural
  #pragma unroll
  for (int m=0;m<2;m++)
    #pragma unroll
    for (int cf=0;cf<2;cf++)
      #pragma unroll
      for (int mf=0;mf<4;mf++) aqk[m][cf][mf] = (f32x4){0,0,0,0};
  #pragma unroll
  for (int rf=0;rf<4;rf++){ av[rf][0]=(f32x4){0,0,0,0}; av[rf][1]=(f32x4){0,0,0,0}; }

  #pragma unroll
  for (int kt=0; kt<8; kt++){
    f16x8 xf[4], wf[3][2];
    #pragma unroll
    for (int rf=0; rf<4; rf++){
      int r = (rf<<4) + lr;
      int idx = ((r<<8) + (kt<<5) + (g<<3)) ^ ((r&7)<<3);
      xf[rf] = *(const f16x8*)&Xs[idx];
    }
    #pragma unroll
    for (int m=0;m<3;m++)
      #pragma unroll
      for (int cf=0;cf<2;cf++){
        int n = (w<<5) + (cf<<4) + lr;
        wf[m][cf] = *(const f16x8*)(Wqkv + (size_t)m*65536 + (size_t)n*256 + (kt<<5) + (g<<3));
      }
    __builtin_amdgcn_s_setprio(1);
    #pragma unroll
    for (int m=0;m<2;m++)
      #pragma unroll
      for (int cf=0;cf<2;cf++)
        #pragma unroll
        for (int mf=0;mf<4;mf++)
          aqk[m][cf][mf] = __builtin_amdgcn_mfma_f32_16x16x32_f16(wf[m][cf], xf[mf], aqk[m][cf][mf], 0,0,0);
    #pragma unroll
    for (int rf=0;rf<4;rf++)
      #pragma unroll
      for (int cf=0;cf<2;cf++)
        av[rf][cf] = __builtin_amdgcn_mfma_f32_16x16x32_f16(xf[rf], wf[2][cf], av[rf][cf], 0,0,0);
    __builtin_amdgcn_s_setprio(0);
  }
  // scatter: Q/K f16x4 along d; V f16x4 along q
  #pragma unroll
  for (int cf=0; cf<2; cf++){
    int n0 = (w<<5) + (cf<<4) + (g<<2);     // 4 consecutive n
    int headq = n0>>6, d0 = n0&63;
    int hbq = headq<<12;
    #pragma unroll
    for (int mf=0; mf<4; mf++){
      int q = (mf<<4) + lr;
      int base = (q<<6) + (((d0>>3) ^ (q&7))<<3) + (d0&7);
      f16x4 oq, ok;
      #pragma unroll
      for (int i=0;i<4;i++){ oq[i]=(h16)aqk[0][cf][mf][i]; ok[i]=(h16)aqk[1][cf][mf][i]; }
      *(f16x4*)&Qs[hbq + base] = oq;
      *(f16x4*)&Ks[hbq + base] = ok;
    }
    int nv = (w<<5) + (cf<<4) + lr;
    int headv = nv>>6, dv = nv&63;
    int hbv = headv<<12;
    int vkey = (dv + (dv>>3)) & 7;
    #pragma unroll
    for (int rf=0; rf<4; rf++){
      int q0 = (rf<<4) + (g<<2);
      f16x4 ov;
      #pragma unroll
      for (int i=0;i<4;i++) ov[i]=(h16)av[rf][cf][i];
      *(f16x4*)&VsT[hbv + (dv<<6) + (((q0>>3) ^ vkey)<<3) + (q0&7)] = ov;
    }
  }
  __syncthreads();
  #pragma unroll
  for (int sl=0; sl<2; sl++){
    int slot = w + (sl<<3);
    int head = slot>>2, q0 = (slot&3)<<4;
    const int hb = head<<12;
    f16x8 qf[2];
    #pragma unroll
    for (int ks=0; ks<2; ks++)
      qf[ks] = *(const f16x8*)&Qs[hb + ((q0+lr)<<6) + (((g + (ks<<2)) ^ (lr&7))<<3)];
    f32x4 sa[4];
    #pragma unroll
    for (int mm=0;mm<4;mm++) sa[mm] = (f32x4){0,0,0,0};
    __builtin_amdgcn_s_setprio(1);
    #pragma unroll
    for (int ks=0; ks<2; ks++)
      #pragma unroll
      for (int mm=0;mm<4;mm++){
        int krow = (mm<<4) + lr;
        f16x8 af = *(const f16x8*)&Ks[hb + (krow<<6) + (((g + (ks<<2)) ^ (krow&7))<<3)];
        sa[mm] = __builtin_amdgcn_mfma_f32_16x16x32_f16(af, qf[ks], sa[mm], 0,0,0);
      }
    __builtin_amdgcn_s_setprio(0);
    float pmax = -1e30f;
    #pragma unroll
    for (int mm=0;mm<4;mm++)
      #pragma unroll
      for (int i=0;i<4;i++) pmax = fmaxf(pmax, sa[mm][i]);
    pmax = fmaxf(pmax, __shfl_xor(pmax, 16));
    pmax = fmaxf(pmax, __shfl_xor(pmax, 32));
    float ps = 0.f;
    f16x4 pv[4];
    #pragma unroll
    for (int mm=0;mm<4;mm++)
      #pragma unroll
      for (int i=0;i<4;i++){
        float p = __expf(sa[mm][i] - pmax);
        ps += p;
        pv[mm][i] = (h16)p;
      }
    ps += __shfl_xor(ps, 16);
    ps += __shfl_xor(ps, 32);
    const int pbase = w<<10;
    #pragma unroll
    for (int mm=0;mm<4;mm++){
      int k0 = (mm<<4) + (g<<2);
      int unit = k0>>3, off = k0&7;
      *(f16x4*)&Ps[pbase + (lr<<6) + ((unit ^ (lr&7))<<3) + off] = pv[mm];
    }
    f32x4 oc[4];
    #pragma unroll
    for (int cf=0;cf<4;cf++) oc[cf] = (f32x4){0,0,0,0};
    __builtin_amdgcn_s_setprio(1);
    #pragma unroll
    for (int ks=0; ks<2; ks++){
      f16x8 pa = *(const f16x8*)&Ps[pbase + (lr<<6) + (((g + (ks<<2)) ^ (lr&7))<<3)];
      #pragma unroll
      for (int cf=0;cf<4;cf++){
        int d = (cf<<4) + lr;
        int key = (d + (d>>3)) & 7;
        f16x8 bf = *(const f16x8*)&VsT[hb + (d<<6) + (((g + (ks<<2)) ^ key)<<3)];
        oc[cf] = __builtin_amdgcn_mfma_f32_16x16x32_f16(pa, bf, oc[cf], 0,0,0);
      }
    }
    __builtin_amdgcn_s_setprio(0);
    float linv = 1.0f/(ps*8.0f);
    #pragma unroll
    for (int i=0;i<4;i++){
      float li = __shfl(linv, (g<<4) + (g<<2) + i);
      int row = m0 + q0 + (g<<2) + i;
      #pragma unroll
      for (int cf=0;cf<4;cf++){
        int col = (head<<6) + (cf<<4) + lr;
        size_t ga = (size_t)row*256 + col;
        Out[ga] = oc[cf][i]*li + A[ga];
      }
    }
  }
}

// ---------------------------------------------------------------- fused QKV projection (inter): swapped, ushort4 stores
template<bool DOLN>
__global__ __launch_bounds__(512) void k_qkv(
    const float* __restrict__ X,
    const float* __restrict__ lng, const float* __restrict__ lnb,
    const h16* __restrict__ Bt0,
    h16* __restrict__ Qh, h16* __restrict__ Kh, h16* __restrict__ Vh){
  __shared__ h16 Xs[64*256];
  const int tid = threadIdx.x, lane = tid&63, w = tid>>6;
  const int lr = lane&15, g = lane>>4;
  const int m0 = blockIdx.x<<6;
  {
    float4 gg, bb;
    if (DOLN){ gg = *(const float4*)(lng + (lane<<2)); bb = *(const float4*)(lnb + (lane<<2)); }
    #pragma unroll
    for (int rr=0; rr<8; rr++){
      int r = (w<<3) + rr;
      float4 v = *(const float4*)(X + (size_t)(m0+r)*256 + (lane<<2));
      if (DOLN){
        float sm = wave_sum(v.x+v.y+v.z+v.w);
        float sq = wave_sum(v.x*v.x+v.y*v.y+v.z*v.z+v.w*v.w);
        float mean = sm*(1.f/256.f);
        float rs = rsqrtf(sq*(1.f/256.f) - mean*mean + 1e-10f);
        v.x=(v.x-mean)*rs*gg.x+bb.x; v.y=(v.y-mean)*rs*gg.y+bb.y;
        v.z=(v.z-mean)*rs*gg.z+bb.z; v.w=(v.w-mean)*rs*gg.w+bb.w;
      }
      f16x4 o; o[0]=(h16)v.x; o[1]=(h16)v.y; o[2]=(h16)v.z; o[3]=(h16)v.w;
      int idx = ((r<<8) + (lane<<2)) ^ ((r&7)<<3);
      *(f16x4*)&Xs[idx] = o;
    }
  }
  __syncthreads();
  f32x4 acc[3][4];   // [mat][mf], swapped: row=n-local(16), col=m
  #pragma unroll
  for (int m=0;m<3;m++)
    #pragma unroll
    for (int mf=0;mf<4;mf++) acc[m][mf] = (f32x4){0,0,0,0};
  #pragma unroll
  for (int i=0; i<8; i++){
    int kt = (i + w) & 7;
    f16x8 xf[4], wfr[3];
    #pragma unroll
    for (int mf=0; mf<4; mf++){
      int r = (mf<<4) + lr;
      int idx = ((r<<8) + (kt<<5) + (g<<3)) ^ ((r&7)<<3);
      xf[mf] = *(const f16x8*)&Xs[idx];
    }
    #pragma unroll
    for (int m=0;m<3;m++){
      int n = (w<<4) + lr;
      wfr[m] = *(const f16x8*)(Bt0 + (size_t)m*65536 + (size_t)n*256 + (kt<<5) + (g<<3));
    }
    __builtin_amdgcn_s_setprio(1);
    #pragma unroll
    for (int m=0;m<3;m++)
      #pragma unroll
      for (int mf=0;mf<4;mf++)
        acc[m][mf] = __builtin_amdgcn_mfma_f32_16x16x32_f16(wfr[m], xf[mf], acc[m][mf], 0,0,0);
    __builtin_amdgcn_s_setprio(0);
  }
  const int n0 = (w<<4) + (g<<2);
  #pragma unroll
  for (int m=0;m<3;m++){
    h16* dst = (m==0)?Qh:(m==1)?Kh:Vh;
    #pragma unroll
    for (int mf=0; mf<4; mf++){
      int row = m0 + (mf<<4) + lr;
      f16x4 o;
      #pragma unroll
      for (int i=0;i<4;i++) o[i] = (h16)acc[m][mf][i];
      *(f16x4*)(dst + (size_t)row*128 + n0) = o;
    }
  }
}

// ---------------------------------------------------------------- MFMA attention (inter, r10-verified)
template<int NT, int QG>
__global__ __launch_bounds__(256) void k_attn16(
    const h16* __restrict__ Qh, const h16* __restrict__ Kh, const h16* __restrict__ Vh,
    const float* __restrict__ Resid, float* __restrict__ Out, int hbase){
  __shared__ h16 Ks[64*64];
  __shared__ h16 VsT[64*64];
  __shared__ h16 Ps[4*QG*16*64];
  const int tid = threadIdx.x, lane = tid&63, w = tid>>6;
  const int lr = lane&15, g = lane>>4;
  int hh, t=0, qc=0, s=0;
  if (NT==1){ s = blockIdx.x; hh = blockIdx.y; }
  else      { hh = blockIdx.x; t = blockIdx.y; qc = blockIdx.z; }
  const int ccol = hh<<6;
  const int gcol = (hbase+hh)<<6;

  f16x8 qf[QG][2];
  #pragma unroll
  for (int grp=0; grp<QG; grp++){
    int ql = grp*64 + (w<<4) + lr;
    size_t m = (NT==1) ? ((size_t)s*64 + ql) : (((size_t)qc*(64*QG) + ql)*64 + t);
    const h16* qp = Qh + m*128 + ccol + (g<<3);
    qf[grp][0] = *(const f16x8*)qp;
    qf[grp][1] = *(const f16x8*)(qp + 32);
  }

  f32x4 oc[QG][4];
  float m_r[QG], l_r[QG];
  #pragma unroll
  for (int grp=0; grp<QG; grp++){
    #pragma unroll
    for (int cf=0;cf<4;cf++) oc[grp][cf] = (f32x4){0,0,0,0};
    m_r[grp] = -1e30f; l_r[grp] = 0.f;
  }

  for (int kb=0; kb<NT; kb++){
    __syncthreads();
    #pragma unroll
    for (int it=0; it<2; it++){
      int u = it*256 + tid;
      int row = u>>3, un = u&7;
      size_t m = (NT==1) ? ((size_t)s*64 + row) : (((size_t)kb*64 + row)*64 + t);
      f16x8 kv = *(const f16x8*)(Kh + m*128 + ccol + (un<<3));
      *(f16x8*)&Ks[(row<<6) + ((un ^ (row&7))<<3)] = kv;
      f16x8 vv = *(const f16x8*)(Vh + m*128 + ccol + (un<<3));
      #pragma unroll
      for (int j=0;j<8;j++){
        int d = (un<<3) + j;
        int key = (d + un) & 7;
        VsT[(d<<6) + ((((row>>3) ^ key))<<3) + (row&7)] = vv[j];
      }
    }
    __syncthreads();
    #pragma unroll
    for (int grp=0; grp<QG; grp++){
      f32x4 sa[4];
      #pragma unroll
      for (int mm=0;mm<4;mm++) sa[mm] = (f32x4){0,0,0,0};
      __builtin_amdgcn_s_setprio(1);
      #pragma unroll
      for (int ks=0; ks<2; ks++){
        #pragma unroll
        for (int mm=0;mm<4;mm++){
          int krow = (mm<<4) + lr;
          f16x8 af = *(const f16x8*)&Ks[(krow<<6) + (((g + (ks<<2)) ^ (krow&7))<<3)];
          sa[mm] = __builtin_amdgcn_mfma_f32_16x16x32_f16(af, qf[grp][ks], sa[mm], 0,0,0);
        }
      }
      __builtin_amdgcn_s_setprio(0);
      float pmax = -1e30f;
      #pragma unroll
      for (int mm=0;mm<4;mm++)
        #pragma unroll
        for (int i=0;i<4;i++) pmax = fmaxf(pmax, sa[mm][i]);
      pmax = fmaxf(pmax, __shfl_xor(pmax, 16));
      pmax = fmaxf(pmax, __shfl_xor(pmax, 32));
      float mn = fmaxf(m_r[grp], pmax);
      float sca = __expf(m_r[grp] - mn);
      m_r[grp] = mn;
      float ps = 0.f;
      f16x4 pv[4];
      #pragma unroll
      for (int mm=0;mm<4;mm++){
        #pragma unroll
        for (int i=0;i<4;i++){
          float p = __expf(sa[mm][i] - mn);
          ps += p;
          pv[mm][i] = (h16)p;
        }
      }
      ps += __shfl_xor(ps, 16);
      ps += __shfl_xor(ps, 32);
      l_r[grp] = l_r[grp]*sca + ps;
      const int pbase = ((w*QG + grp)<<10);
      #pragma unroll
      for (int mm=0;mm<4;mm++){
        int k0 = (mm<<4) + (g<<2);
        int unit = k0>>3, off = k0&7;
        *(f16x4*)&Ps[pbase + (lr<<6) + ((unit ^ (lr&7))<<3) + off] = pv[mm];
      }
      #pragma unroll
      for (int i=0;i<4;i++){
        float si = __shfl(sca, (g<<4) + (g<<2) + i);
        #pragma unroll
        for (int cf=0;cf<4;cf++) oc[grp][cf][i] *= si;
      }
      __builtin_amdgcn_s_setprio(1);
      #pragma unroll
      for (int ks=0; ks<2; ks++){
        f16x8 pa = *(const f16x8*)&Ps[pbase + (lr<<6) + (((g + (ks<<2)) ^ (lr&7))<<3)];
        #pragma unroll
        for (int cf=0;cf<4;cf++){
          int d = (cf<<4) + lr;
          int key = (d + (d>>3)) & 7;
          f16x8 bf = *(const f16x8*)&VsT[(d<<6) + (((g + (ks<<2)) ^ key)<<3)];
          oc[grp][cf] = __builtin_amdgcn_mfma_f32_16x16x32_f16(pa, bf, oc[grp][cf], 0,0,0);
        }
      }
      __builtin_amdgcn_s_setprio(0);
    }
  }
  #pragma unroll
  for (int grp=0; grp<QG; grp++){
    float linv = 1.0f/(l_r[grp]*8.0f);
    #pragma unroll
    for (int i=0;i<4;i++){
      float li = __shfl(linv, (g<<4) + (g<<2) + i);
      int ql = grp*64 + (w<<4) + (g<<2) + i;
      size_t m = (NT==1) ? ((size_t)s*64 + ql) : (((size_t)qc*(64*QG) + ql)*64 + t);
      #pragma unroll
      for (int cf=0;cf<4;cf++){
        int d = (cf<<4) + lr;
        size_t ga = m*256 + gcol + d;
        Out[ga] = oc[grp][cf][i]*li + Resid[ga];
      }
    }
  }
}

// ---------------------------------------------------------------- MFMA FFN v5b — swapped GEMM1 (vectorized relu writes)
__global__ __launch_bounds__(512,1) void k_ffn5(
    const float* X, float* Out,
    const float* __restrict__ lng, const float* __restrict__ lnb,
    const h16* __restrict__ W1t, const float* __restrict__ b1,
    const h16* __restrict__ W2t, const float* __restrict__ b2){
  __shared__ h16 Xs[64*256];
  __shared__ h16 Hc[64*1024];
  const int tid  = threadIdx.x;
  const int lane = tid & 63;
  const int w    = tid >> 6;
  const int r0   = blockIdx.x << 6;
  const int lr   = lane & 15;
  const int g    = lane >> 4;
  {
    float4 gg = *(const float4*)(lng + (lane<<2));
    float4 bb = *(const float4*)(lnb + (lane<<2));
    #pragma unroll
    for (int rr=0; rr<8; rr++){
      int r = (w<<3) + rr;
      float4 v = *(const float4*)(X + (size_t)(r0+r)*256 + (lane<<2));
      float sm = wave_sum(v.x+v.y+v.z+v.w);
      float sq = wave_sum(v.x*v.x+v.y*v.y+v.z*v.z+v.w*v.w);
      float mean = sm*(1.f/256.f);
      float rs = rsqrtf(sq*(1.f/256.f) - mean*mean + 1e-10f);
      f16x4 o;
      o[0]=(h16)((v.x-mean)*rs*gg.x+bb.x); o[1]=(h16)((v.y-mean)*rs*gg.y+bb.y);
      o[2]=(h16)((v.z-mean)*rs*gg.z+bb.z); o[3]=(h16)((v.w-mean)*rs*gg.w+bb.w);
      int idx = ((r<<8) + (lane<<2)) ^ ((r&7)<<3);
      *(f16x4*)&Xs[idx] = o;
    }
  }
  __syncthreads();
  {
    // GEMM1 swapped: acc1[nf][mf]; row = n-local (4 consecutive), col = m
    f32x4 acc1[8][4];
    #pragma unroll
    for (int a=0;a<8;a++)
      #pragma unroll
      for (int b=0;b<4;b++) acc1[a][b] = (f32x4){0,0,0,0};
    #pragma unroll
    for (int i=0; i<8; i++){
      int kt = (i + w) & 7;
      f16x8 xf[4], wfr[8];
      #pragma unroll
      for (int mf=0; mf<4; mf++){
        int r = (mf<<4) + lr;
        int idx = ((r<<8) + (kt<<5) + (g<<3)) ^ ((r&7)<<3);
        xf[mf] = *(const f16x8*)&Xs[idx];
      }
      #pragma unroll
      for (int nf=0; nf<8; nf++){
        int n = (w<<7) + (nf<<4) + lr;
        wfr[nf] = *(const f16x8*)(W1t + (size_t)n*256 + (kt<<5) + (g<<3));
      }
      __builtin_amdgcn_s_setprio(1);
      #pragma unroll
      for (int nf=0; nf<8; nf++)
        #pragma unroll
        for (int mf=0; mf<4; mf++)
          acc1[nf][mf] = __builtin_amdgcn_mfma_f32_16x16x32_f16(
              wfr[nf], xf[mf], acc1[nf][mf], 0, 0, 0);
      __builtin_amdgcn_s_setprio(0);
    }
    // bias + relu -> Hc, f16x4 along n
    #pragma unroll
    for (int nf=0; nf<8; nf++){
      int n0 = (w<<7) + (nf<<4) + (g<<2);
      float4 bq = *(const float4*)(b1 + n0);
      #pragma unroll
      for (int mf=0; mf<4; mf++){
        int m = (mf<<4) + lr;
        f16x4 o;
        o[0]=(h16)fmaxf(acc1[nf][mf][0]+bq.x,0.f);
        o[1]=(h16)fmaxf(acc1[nf][mf][1]+bq.y,0.f);
        o[2]=(h16)fmaxf(acc1[nf][mf][2]+bq.z,0.f);
        o[3]=(h16)fmaxf(acc1[nf][mf][3]+bq.w,0.f);
        *(f16x4*)&Hc[((m<<10) + n0) ^ ((m&7)<<3)] = o;
      }
    }
  }
  __syncthreads();
  f32x4 acc2[4][2];
  #pragma unroll
  for (int a=0;a<4;a++){ acc2[a][0]=(f32x4){0,0,0,0}; acc2[a][1]=(f32x4){0,0,0,0}; }
  #pragma unroll 4
  for (int i=0; i<32; i++){
    int kt = (i + (w<<2)) & 31;
    f16x8 af[4], bf[2];
    #pragma unroll
    for (int rf=0; rf<4; rf++){
      int r = (rf<<4) + lr;
      int idx = ((r<<10) + (kt<<5) + (g<<3)) ^ ((r&7)<<3);
      af[rf] = *(const f16x8*)&Hc[idx];
    }
    #pragma unroll
    for (int cf=0; cf<2; cf++){
      int n = (w<<5) + (cf<<4) + lr;
      bf[cf] = *(const f16x8*)(W2t + (size_t)n*1024 + (kt<<5) + (g<<3));
    }
    __builtin_amdgcn_s_setprio(1);
    #pragma unroll
    for (int rf=0; rf<4; rf++)
      #pragma unroll
      for (int cf=0; cf<2; cf++)
        acc2[rf][cf] = __builtin_amdgcn_mfma_f32_16x16x32_f16(
            af[rf], bf[cf], acc2[rf][cf], 0, 0, 0);
    __builtin_amdgcn_s_setprio(0);
  }
  #pragma unroll
  for (int cf=0; cf<2; cf++){
    int col = (w<<5) + (cf<<4) + lr;
    float bv = b2[col];
    #pragma unroll
    for (int rf=0; rf<4; rf++){
      #pragma unroll
      for (int i=0;i<4;i++){
        size_t r = (size_t)r0 + (rf<<4) + (g<<2) + i;
        float res = X[r*256 + col];
        Out[r*256 + col] = acc2[rf][cf][i] + bv + res;
      }
    }
  }
}

// ---------------------------------------------------------------- fused head (r13-verified)
__global__ __launch_bounds__(256) void k_head(
    const float* __restrict__ Bb, const h16* __restrict__ Tt,
    const float* __restrict__ predW, const float* __restrict__ predb,
    float* __restrict__ out){
  __shared__ h16 Xs[64*256];
  __shared__ float X1s[64*256];
  __shared__ float lam[64];
  __shared__ float red[4];
  const int tid = threadIdx.x, lane = tid&63, w = tid>>6;
  const int lr = lane&15, g = lane>>4;
  const size_t m0 = (size_t)blockIdx.x<<6;
  #pragma unroll
  for (int it=0; it<16; it++){
    int f4 = it*256 + tid;
    int row = f4>>6, c4 = (f4&63)<<2;
    float4 v = *(const float4*)(Bb + (m0+row)*256 + c4);
    int idx = ((row<<8) + c4) ^ ((row&7)<<3);
    f16x4 o; o[0]=(h16)v.x; o[1]=(h16)v.y; o[2]=(h16)v.z; o[3]=(h16)v.w;
    *(f16x4*)&Xs[idx] = o;
  }
  __syncthreads();
  f32x4 acc[4][4];
  #pragma unroll
  for (int rf=0;rf<4;rf++)
    #pragma unroll
    for (int cf=0;cf<4;cf++) acc[rf][cf] = (f32x4){0,0,0,0};
  #pragma unroll
  for (int kt=0; kt<8; kt++){
    f16x8 af[4], bf[4];
    #pragma unroll
    for (int rf=0; rf<4; rf++){
      int r = (rf<<4) + lr;
      int idx = ((r<<8) + (kt<<5) + (g<<3)) ^ ((r&7)<<3);
      af[rf] = *(const f16x8*)&Xs[idx];
    }
    #pragma unroll
    for (int cf=0; cf<4; cf++){
      int n = (w<<6) + (cf<<4) + lr;
      bf[cf] = *(const f16x8*)(Tt + (size_t)n*256 + (kt<<5) + (g<<3));
    }
    __builtin_amdgcn_s_setprio(1);
    #pragma unroll
    for (int rf=0; rf<4; rf++)
      #pragma unroll
      for (int cf=0; cf<4; cf++)
        acc[rf][cf] = __builtin_amdgcn_mfma_f32_16x16x32_f16(af[rf], bf[cf], acc[rf][cf], 0,0,0);
    __builtin_amdgcn_s_setprio(0);
  }
  #pragma unroll
  for (int cf=0; cf<4; cf++){
    int col = (w<<6) + (cf<<4) + lr;
    #pragma unroll
    for (int rf=0; rf<4; rf++)
      #pragma unroll
      for (int i=0;i<4;i++){
        int r = (rf<<4) + (g<<2) + i;
        X1s[(r<<8) + col] = acc[rf][cf][i];
      }
  }
  __syncthreads();
  float lg[16];
  for (int r=0;r<16;r++){
    int trow = (w<<4) + r;
    float4 xa = *(float4*)&X1s[(trow<<8) + (lane<<2)];
    float4 xc = *(float4*)&X1s[(63<<8) + (lane<<2)];
    lg[r] = wave_sum(xa.x*xc.x + xa.y*xc.y + xa.z*xc.z + xa.w*xc.w);
  }
  if (lane==0){
    #pragma unroll
    for (int r=0;r<16;r++) lam[(w<<4)+r] = lg[r];
  }
  __syncthreads();
  if (tid < 64){
    float v = lam[tid];
    float mx = wave_max(v);
    float p = __expf(v-mx);
    float sm = wave_sum(p);
    lam[tid] = p/sm;
  }
  __syncthreads();
  float ag = 0.f;
  for (int t=0;t<64;t++)
    ag += lam[t]*(float)Xs[((t<<8)+tid) ^ ((t&7)<<3)];
  float wsum = wave_sum(ag * predW[tid]);
  if (lane==0) red[w] = wsum;
  __syncthreads();
  if (tid==0) out[blockIdx.x] = red[0]+red[1]+red[2]+red[3] + predb[0];
}

// ================================================================ launch
extern "C" void kernel_launch(void* const* d_in, const int* in_sizes, int n_in,
                              void* d_out, int out_size, void* d_ws, size_t ws_size,
                              hipStream_t stream){
  const float* x       = (const float*)d_in[0];
  const float* gate_W  = (const float*)d_in[1];
  const float* gate_b  = (const float*)d_in[2];
  const float* embed_W = (const float*)d_in[3];
  const float* ln0_g   = (const float*)d_in[4];
  const float* ln0_b   = (const float*)d_in[5];
  const float* iln_g   = (const float*)d_in[9];
  const float* iln_b   = (const float*)d_in[10];
  const float* iW1     = (const float*)d_in[11];
  const float* ib1     = (const float*)d_in[12];
  const float* iW2     = (const float*)d_in[13];
  const float* ib2     = (const float*)d_in[14];
  const float* eln1_g  = (const float*)d_in[18];
  const float* eln1_b  = (const float*)d_in[19];
  const float* eln2_g  = (const float*)d_in[20];
  const float* eln2_b  = (const float*)d_in[21];
  const float* eW1     = (const float*)d_in[22];
  const float* eb1     = (const float*)d_in[23];
  const float* eW2     = (const float*)d_in[24];
  const float* eb2     = (const float*)d_in[25];
  const float* temp_W  = (const float*)d_in[26];
  const float* pred_W  = (const float*)d_in[27];
  const float* pred_b  = (const float*)d_in[28];
  float* out = (float*)d_out;

  float* pe    = (float*)d_ws;
  float* gate  = pe + 16384;
  h16* fQKV = (h16*)((char*)d_ws + ((size_t)4<<20));
  h16* fE   = fQKV + 393216;
  h16* fT   = fE + 32768;
  h16* fW1i = fT + 65536;
  h16* fW2i = fW1i + 262144;
  h16* fW1e = fW2i + 262144;
  h16* fW2e = fW1e + 262144;
  const size_t MR = (size_t)65536*256, MH = (size_t)65536*128;
  float* A  = (float*)((char*)d_ws + ((size_t)8<<20));
  float* Bb = A + MR;
  h16* Qh = (h16*)(Bb + MR);
  h16* Kh = Qh + MH;
  h16* Vh = Kh + MH;

  k_pe  <<<64,  256, 0, stream>>>(pe);
  k_gate<<<1024, 64, 0, stream>>>(x, gate_W, gate_b, gate);
  k_t16all<<<1504,256,0,stream>>>(
      (const float*)d_in[6],(const float*)d_in[7],(const float*)d_in[8],
      (const float*)d_in[15],(const float*)d_in[16],(const float*)d_in[17],
      embed_W, temp_W, iW1, iW2, eW1, eW2, fQKV);

  // A = LN0(gate*x @ embed_W + pe)
  k_embed<<<1024,256,0,stream>>>(x, fE, pe, gate, ln0_g, ln0_b, A);

  // fused intra QKV+attention: r -> Bb
  k_intra<<<1024,512,0,stream>>>(A, fQKV, Bb);
  k_ffn5<<<1024,512,0,stream>>>(Bb, Bb, iln_g, iln_b, fW1i, ib1, fW2i, ib2);

  // inter attention (transposed batching), LN1 fused into QKV; r2 -> Bb
  for (int hp=0; hp<2; hp++){
    int hb = hp*2;
    k_qkv<true><<<1024,512,0,stream>>>(Bb, eln1_g, eln1_b,
        fQKV + 3*65536 + hb*16384, Qh, Kh, Vh);
    k_attn16<16,1><<<dim3(2,64,16),256,0,stream>>>(Qh, Kh, Vh, Bb, Bb, hb);
  }
  k_ffn5<<<1024,512,0,stream>>>(Bb, Bb, eln2_g, eln2_b, fW1e, eb1, fW2e, eb2);

  // fused head
  k_head<<<1024,256,0,stream>>>(Bb, fT, pred_W, pred_b, out);
}

// Round 16
// 711.826 us; speedup vs baseline: 1.2207x; 1.0089x over previous
//
#include <hip/hip_runtime.h>

// S=1024, T=64, F=128, J=64, E=256, H=4, DH=64. M = S*T = 65536 rows.
// r16: explicit register prefetch of weight B-fragments (depth 1-2) in
// k_ffn5 / k_qkv / k_intra. Everything else identical to r15 (718us).

typedef _Float16 h16;
typedef __attribute__((ext_vector_type(8))) _Float16 f16x8;
typedef __attribute__((ext_vector_type(4))) _Float16 f16x4;
typedef __attribute__((ext_vector_type(4))) float f32x4;

__device__ inline float wave_sum(float v){
  #pragma unroll
  for (int o=32;o;o>>=1) v += __shfl_xor(v,o);
  return v;
}
__device__ inline float wave_max(float v){
  #pragma unroll
  for (int o=32;o;o>>=1) v = fmaxf(v,__shfl_xor(v,o));
  return v;
}

// ---------------------------------------------------------------- pe table
__global__ __launch_bounds__(256) void k_pe(float* __restrict__ pe){
  int t = blockIdx.x, i = threadIdx.x;
  float two_i = (float)((i>>1)<<1);
  float dv = powf(100004.0f, two_i*(1.0f/256.0f));
  float v = (float)t / dv;
  pe[t*256+i] = (i&1) ? cosf(v) : sinf(v);
}

// ---------------------------------------------------------------- gate softmax
__global__ __launch_bounds__(64) void k_gate(const float* __restrict__ x,
    const float* __restrict__ gW, const float* __restrict__ gb,
    float* __restrict__ gate){
  int s = blockIdx.x, lane = threadIdx.x;
  __shared__ float xg[64];
  xg[lane] = x[((size_t)s*64+63)*192 + 128 + lane];
  __syncthreads();
  float a0 = gb[lane], a1 = gb[64+lane];
  #pragma unroll 4
  for (int j=0;j<64;j++){
    float xv = xg[j];
    a0 += xv*gW[j*128+lane];
    a1 += xv*gW[j*128+64+lane];
  }
  float mx = wave_max(fmaxf(a0,a1));
  float e0 = __expf(a0-mx), e1 = __expf(a1-mx);
  float sm = wave_sum(e0+e1);
  gate[s*128+lane]    = e0/sm;
  gate[s*128+64+lane] = e1/sm;
}

// ---------------------------------------------------------------- all weight transposes -> f16 [n][k]
__global__ __launch_bounds__(256) void k_t16all(
    const float* __restrict__ q1, const float* __restrict__ k1, const float* __restrict__ v1,
    const float* __restrict__ q2, const float* __restrict__ k2, const float* __restrict__ v2,
    const float* __restrict__ embed_W, const float* __restrict__ temp_W,
    const float* __restrict__ iW1, const float* __restrict__ iW2,
    const float* __restrict__ eW1, const float* __restrict__ eW2,
    h16* __restrict__ base){
  __shared__ float tile[32][33];
  const int b = blockIdx.x, tid = threadIdx.x;
  const float* src; h16* dst; int K, N, tb; bool qkv = false;
  if (b < 384){
    int mat = b>>6; tb = b&63; qkv = true; K = 256; N = 256;
    src = (mat==0)?q1:(mat==1)?k1:(mat==2)?v1:(mat==3)?q2:(mat==4)?k2:v2;
    dst = base + mat*65536;
  } else if (b < 416){ tb = b-384;  K=128;  N=256;  src=embed_W; dst=base+393216; }
  else if (b < 480){ tb = b-416;  K=256;  N=256;  src=temp_W;  dst=base+425984; }
  else if (b < 736){ tb = b-480;  K=256;  N=1024; src=iW1;     dst=base+491520; }
  else if (b < 992){ tb = b-736;  K=1024; N=256;  src=iW2;     dst=base+753664; }
  else if (b < 1248){ tb = b-992; K=256;  N=1024; src=eW1;     dst=base+1015808; }
  else               { tb = b-1248; K=1024; N=256; src=eW2;    dst=base+1277952; }
  const int nt = N>>5;
  const int N0 = (tb & (nt-1))<<5;
  const int K0 = (tb/nt)<<5;
  {
    int r = tid>>3, c0 = (tid&7)<<2;
    int k = K0+r, n = N0+c0;
    const float* p = qkv ? (src + ((n>>6)<<14) + (k<<6) + (n&63))
                         : (src + (size_t)k*N + n);
    float4 v = *(const float4*)p;
    tile[r][c0]=v.x; tile[r][c0+1]=v.y; tile[r][c0+2]=v.z; tile[r][c0+3]=v.w;
  }
  __syncthreads();
  {
    int r = tid>>3, c0 = (tid&7)<<2;
    f16x4 o;
    o[0]=(h16)tile[c0][r]; o[1]=(h16)tile[c0+1][r];
    o[2]=(h16)tile[c0+2][r]; o[3]=(h16)tile[c0+3][r];
    *(f16x4*)(dst + (size_t)(N0+r)*K + K0 + c0) = o;
  }
}

// ---------------------------------------------------------------- embed + pe + LN0 (fused)
__global__ __launch_bounds__(256) void k_embed(
    const float* __restrict__ x, const h16* __restrict__ Et,
    const float* __restrict__ pe, const float* __restrict__ gate,
    const float* __restrict__ g0, const float* __restrict__ b0,
    float* __restrict__ A){
  __shared__ char pool[65536];
  h16*  As  = (h16*)pool;
  float* res = (float*)pool;
  const int tid = threadIdx.x, lane = tid&63, w = tid>>6;
  const int lr = lane&15, g = lane>>4;
  const int m0 = blockIdx.x<<6;
  #pragma unroll
  for (int it=0; it<8; it++){
    int f4 = it*256 + tid;
    int row = f4>>5, c4 = (f4&31)<<2;
    float4 v = *(const float4*)(x + (size_t)(m0+row)*192 + c4);
    float4 gg = *(const float4*)(gate + (((m0+row)>>6)<<7) + c4);
    v.x*=gg.x; v.y*=gg.y; v.z*=gg.z; v.w*=gg.w;
    int idx = ((row<<7) + c4) ^ ((row&7)<<3);
    f16x4 o; o[0]=(h16)v.x; o[1]=(h16)v.y; o[2]=(h16)v.z; o[3]=(h16)v.w;
    *(f16x4*)&As[idx] = o;
  }
  __syncthreads();
  f32x4 acc[4][4];
  #pragma unroll
  for (int a=0;a<4;a++)
    #pragma unroll
    for (int b=0;b<4;b++) acc[a][b] = (f32x4){0,0,0,0};
  #pragma unroll
  for (int i=0; i<4; i++){
    int kt = (i + w) & 3;
    f16x8 af[4], bf[4];
    #pragma unroll
    for (int rf=0; rf<4; rf++){
      int r = (rf<<4) + lr;
      int idx = ((r<<7) + (kt<<5) + (g<<3)) ^ ((r&7)<<3);
      af[rf] = *(const f16x8*)&As[idx];
    }
    #pragma unroll
    for (int cf=0; cf<4; cf++){
      int n = (w<<6) + (cf<<4) + lr;
      bf[cf] = *(const f16x8*)(Et + (size_t)n*128 + (kt<<5) + (g<<3));
    }
    __builtin_amdgcn_s_setprio(1);
    #pragma unroll
    for (int rf=0; rf<4; rf++)
      #pragma unroll
      for (int cf=0; cf<4; cf++)
        acc[rf][cf] = __builtin_amdgcn_mfma_f32_16x16x32_f16(af[rf], bf[cf], acc[rf][cf], 0,0,0);
    __builtin_amdgcn_s_setprio(0);
  }
  __syncthreads();
  #pragma unroll
  for (int cf=0; cf<4; cf++){
    int col = (w<<6) + (cf<<4) + lr;
    #pragma unroll
    for (int rf=0; rf<4; rf++)
      #pragma unroll
      for (int i=0;i<4;i++){
        int r = (rf<<4) + (g<<2) + i;
        res[(r<<8) + col] = acc[rf][cf][i] + pe[(r<<8) + col];
      }
  }
  __syncthreads();
  {
    float4 gg = *(const float4*)(g0 + (lane<<2));
    float4 bb = *(const float4*)(b0 + (lane<<2));
    for (int rr=0; rr<16; rr++){
      int r = (w<<4) + rr;
      float4 v = *(float4*)&res[(r<<8) + (lane<<2)];
      float sm = wave_sum(v.x+v.y+v.z+v.w);
      float sq = wave_sum(v.x*v.x+v.y*v.y+v.z*v.z+v.w*v.w);
      float mean = sm*(1.f/256.f);
      float rs = rsqrtf(sq*(1.f/256.f) - mean*mean + 1e-10f);
      float4 o;
      o.x=(v.x-mean)*rs*gg.x+bb.x; o.y=(v.y-mean)*rs*gg.y+bb.y;
      o.z=(v.z-mean)*rs*gg.z+bb.z; o.w=(v.w-mean)*rs*gg.w+bb.w;
      *(float4*)(A + (size_t)(m0+r)*256 + (lane<<2)) = o;
    }
  }
}

// ---------------------------------------------------------------- fused intra (r15 + depth-1 W prefetch)
__global__ __launch_bounds__(512,1) void k_intra(
    const float* __restrict__ A, const h16* __restrict__ Wqkv,
    float* __restrict__ Out){
  __shared__ h16 Xs[64*256];
  __shared__ h16 Qs[4*64*64];
  __shared__ h16 Ks[4*64*64];
  __shared__ h16 VsT[4*64*64];
  __shared__ h16 Ps[8*16*64];
  const int tid = threadIdx.x, lane = tid&63, w = tid>>6;
  const int lr = lane&15, g = lane>>4;
  const int m0 = blockIdx.x<<6;
  #pragma unroll
  for (int rr=0; rr<8; rr++){
    int r = (w<<3) + rr;
    float4 v = *(const float4*)(A + (size_t)(m0+r)*256 + (lane<<2));
    f16x4 o; o[0]=(h16)v.x; o[1]=(h16)v.y; o[2]=(h16)v.z; o[3]=(h16)v.w;
    int idx = ((r<<8) + (lane<<2)) ^ ((r&7)<<3);
    *(f16x4*)&Xs[idx] = o;
  }

  f32x4 aqk[2][2][4];
  f32x4 av[4][2];
  #pragma unroll
  for (int m=0;m<2;m++)
    #pragma unroll
    for (int cf=0;cf<2;cf++)
      #pragma unroll
      for (int mf=0;mf<4;mf++) aqk[m][cf][mf] = (f32x4){0,0,0,0};
  #pragma unroll
  for (int rf=0;rf<4;rf++){ av[rf][0]=(f32x4){0,0,0,0}; av[rf][1]=(f32x4){0,0,0,0}; }

  // prefetch kt=0 weight frags
  f16x8 wp[3][2];
  #pragma unroll
  for (int m=0;m<3;m++)
    #pragma unroll
    for (int cf=0;cf<2;cf++){
      int n = (w<<5) + (cf<<4) + lr;
      wp[m][cf] = *(const f16x8*)(Wqkv + (size_t)m*65536 + (size_t)n*256 + (g<<3));
    }
  __syncthreads();

  #pragma unroll
  for (int kt=0; kt<8; kt++){
    f16x8 xf[4], wf[3][2];
    #pragma unroll
    for (int m=0;m<3;m++)
      #pragma unroll
      for (int cf=0;cf<2;cf++) wf[m][cf] = wp[m][cf];
    if (kt<7){
      #pragma unroll
      for (int m=0;m<3;m++)
        #pragma unroll
        for (int cf=0;cf<2;cf++){
          int n = (w<<5) + (cf<<4) + lr;
          wp[m][cf] = *(const f16x8*)(Wqkv + (size_t)m*65536 + (size_t)n*256 + ((kt+1)<<5) + (g<<3));
        }
    }
    #pragma unroll
    for (int rf=0; rf<4; rf++){
      int r = (rf<<4) + lr;
      int idx = ((r<<8) + (kt<<5) + (g<<3)) ^ ((r&7)<<3);
      xf[rf] = *(const f16x8*)&Xs[idx];
    }
    __builtin_amdgcn_s_setprio(1);
    #pragma unroll
    for (int m=0;m<2;m++)
      #pragma unroll
      for (int cf=0;cf<2;cf++)
        #pragma unroll
        for (int mf=0;mf<4;mf++)
          aqk[m][cf][mf] = __builtin_amdgcn_mfma_f32_16x16x32_f16(wf[m][cf], xf[mf], aqk[m][cf][mf], 0,0,0);
    #pragma unroll
    for (int rf=0;rf<4;rf++)
      #pragma unroll
      for (int cf=0;cf<2;cf++)
        av[rf][cf] = __builtin_amdgcn_mfma_f32_16x16x32_f16(xf[rf], wf[2][cf], av[rf][cf], 0,0,0);
    __builtin_amdgcn_s_setprio(0);
  }
  #pragma unroll
  for (int cf=0; cf<2; cf++){
    int n0 = (w<<5) + (cf<<4) + (g<<2);
    int headq = n0>>6, d0 = n0&63;
    int hbq = headq<<12;
    #pragma unroll
    for (int mf=0; mf<4; mf++){
      int q = (mf<<4) + lr;
      int base = (q<<6) + (((d0>>3) ^ (q&7))<<3) + (d0&7);
      f16x4 oq, ok;
      #pragma unroll
      for (int i=0;i<4;i++){ oq[i]=(h16)aqk[0][cf][mf][i]; ok[i]=(h16)aqk[1][cf][mf][i]; }
      *(f16x4*)&Qs[hbq + base] = oq;
      *(f16x4*)&Ks[hbq + base] = ok;
    }
    int nv = (w<<5) + (cf<<4) + lr;
    int headv = nv>>6, dv = nv&63;
    int hbv = headv<<12;
    int vkey = (dv + (dv>>3)) & 7;
    #pragma unroll
    for (int rf=0; rf<4; rf++){
      int q0 = (rf<<4) + (g<<2);
      f16x4 ov;
      #pragma unroll
      for (int i=0;i<4;i++) ov[i]=(h16)av[rf][cf][i];
      *(f16x4*)&VsT[hbv + (dv<<6) + (((q0>>3) ^ vkey)<<3) + (q0&7)] = ov;
    }
  }
  __syncthreads();
  #pragma unroll
  for (int sl=0; sl<2; sl++){
    int slot = w + (sl<<3);
    int head = slot>>2, q0 = (slot&3)<<4;
    const int hb = head<<12;
    f16x8 qf[2];
    #pragma unroll
    for (int ks=0; ks<2; ks++)
      qf[ks] = *(const f16x8*)&Qs[hb + ((q0+lr)<<6) + (((g + (ks<<2)) ^ (lr&7))<<3)];
    f32x4 sa[4];
    #pragma unroll
    for (int mm=0;mm<4;mm++) sa[mm] = (f32x4){0,0,0,0};
    __builtin_amdgcn_s_setprio(1);
    #pragma unroll
    for (int ks=0; ks<2; ks++)
      #pragma unroll
      for (int mm=0;mm<4;mm++){
        int krow = (mm<<4) + lr;
        f16x8 af = *(const f16x8*)&Ks[hb + (krow<<6) + (((g + (ks<<2)) ^ (krow&7))<<3)];
        sa[mm] = __builtin_amdgcn_mfma_f32_16x16x32_f16(af, qf[ks], sa[mm], 0,0,0);
      }
    __builtin_amdgcn_s_setprio(0);
    float pmax = -1e30f;
    #pragma unroll
    for (int mm=0;mm<4;mm++)
      #pragma unroll
      for (int i=0;i<4;i++) pmax = fmaxf(pmax, sa[mm][i]);
    pmax = fmaxf(pmax, __shfl_xor(pmax, 16));
    pmax = fmaxf(pmax, __shfl_xor(pmax, 32));
    float ps = 0.f;
    f16x4 pv[4];
    #pragma unroll
    for (int mm=0;mm<4;mm++)
      #pragma unroll
      for (int i=0;i<4;i++){
        float p = __expf(sa[mm][i] - pmax);
        ps += p;
        pv[mm][i] = (h16)p;
      }
    ps += __shfl_xor(ps, 16);
    ps += __shfl_xor(ps, 32);
    const int pbase = w<<10;
    #pragma unroll
    for (int mm=0;mm<4;mm++){
      int k0 = (mm<<4) + (g<<2);
      int unit = k0>>3, off = k0&7;
      *(f16x4*)&Ps[pbase + (lr<<6) + ((unit ^ (lr&7))<<3) + off] = pv[mm];
    }
    f32x4 oc[4];
    #pragma unroll
    for (int cf=0;cf<4;cf++) oc[cf] = (f32x4){0,0,0,0};
    __builtin_amdgcn_s_setprio(1);
    #pragma unroll
    for (int ks=0; ks<2; ks++){
      f16x8 pa = *(const f16x8*)&Ps[pbase + (lr<<6) + (((g + (ks<<2)) ^ (lr&7))<<3)];
      #pragma unroll
      for (int cf=0;cf<4;cf++){
        int d = (cf<<4) + lr;
        int key = (d + (d>>3)) & 7;
        f16x8 bf = *(const f16x8*)&VsT[hb + (d<<6) + (((g + (ks<<2)) ^ key)<<3)];
        oc[cf] = __builtin_amdgcn_mfma_f32_16x16x32_f16(pa, bf, oc[cf], 0,0,0);
      }
    }
    __builtin_amdgcn_s_setprio(0);
    float linv = 1.0f/(ps*8.0f);
    #pragma unroll
    for (int i=0;i<4;i++){
      float li = __shfl(linv, (g<<4) + (g<<2) + i);
      int row = m0 + q0 + (g<<2) + i;
      #pragma unroll
      for (int cf=0;cf<4;cf++){
        int col = (head<<6) + (cf<<4) + lr;
        size_t ga = (size_t)row*256 + col;
        Out[ga] = oc[cf][i]*li + A[ga];
      }
    }
  }
}

// ---------------------------------------------------------------- fused QKV projection (r15 + depth-2 W prefetch)
template<bool DOLN>
__global__ __launch_bounds__(512) void k_qkv(
    const float* __restrict__ X,
    const float* __restrict__ lng, const float* __restrict__ lnb,
    const h16* __restrict__ Bt0,
    h16* __restrict__ Qh, h16* __restrict__ Kh, h16* __restrict__ Vh){
  __shared__ h16 Xs[64*256];
  const int tid = threadIdx.x, lane = tid&63, w = tid>>6;
  const int lr = lane&15, g = lane>>4;
  const int m0 = blockIdx.x<<6;
  {
    float4 gg, bb;
    if (DOLN){ gg = *(const float4*)(lng + (lane<<2)); bb = *(const float4*)(lnb + (lane<<2)); }
    #pragma unroll
    for (int rr=0; rr<8; rr++){
      int r = (w<<3) + rr;
      float4 v = *(const float4*)(X + (size_t)(m0+r)*256 + (lane<<2));
      if (DOLN){
        float sm = wave_sum(v.x+v.y+v.z+v.w);
        float sq = wave_sum(v.x*v.x+v.y*v.y+v.z*v.z+v.w*v.w);
        float mean = sm*(1.f/256.f);
        float rs = rsqrtf(sq*(1.f/256.f) - mean*mean + 1e-10f);
        v.x=(v.x-mean)*rs*gg.x+bb.x; v.y=(v.y-mean)*rs*gg.y+bb.y;
        v.z=(v.z-mean)*rs*gg.z+bb.z; v.w=(v.w-mean)*rs*gg.w+bb.w;
      }
      f16x4 o; o[0]=(h16)v.x; o[1]=(h16)v.y; o[2]=(h16)v.z; o[3]=(h16)v.w;
      int idx = ((r<<8) + (lane<<2)) ^ ((r&7)<<3);
      *(f16x4*)&Xs[idx] = o;
    }
  }
  f32x4 acc[3][4];
  #pragma unroll
  for (int m=0;m<3;m++)
    #pragma unroll
    for (int mf=0;mf<4;mf++) acc[m][mf] = (f32x4){0,0,0,0};
  // depth-2 prefetch (slots for i and i+1)
  f16x8 wp[2][3];
  #pragma unroll
  for (int s=0;s<2;s++){
    int kt = (s + w) & 7;
    #pragma unroll
    for (int m=0;m<3;m++){
      int n = (w<<4) + lr;
      wp[s][m] = *(const f16x8*)(Bt0 + (size_t)m*65536 + (size_t)n*256 + (kt<<5) + (g<<3));
    }
  }
  __syncthreads();
  #pragma unroll
  for (int i=0; i<8; i++){
    const int sl = i&1;
    int kt = (i + w) & 7;
    f16x8 xf[4], wfr[3];
    #pragma unroll
    for (int m=0;m<3;m++) wfr[m] = wp[sl][m];
    if (i<6){
      int ktn = ((i+2) + w) & 7;
      #pragma unroll
      for (int m=0;m<3;m++){
        int n = (w<<4) + lr;
        wp[sl][m] = *(const f16x8*)(Bt0 + (size_t)m*65536 + (size_t)n*256 + (ktn<<5) + (g<<3));
      }
    }
    #pragma unroll
    for (int mf=0; mf<4; mf++){
      int r = (mf<<4) + lr;
      int idx = ((r<<8) + (kt<<5) + (g<<3)) ^ ((r&7)<<3);
      xf[mf] = *(const f16x8*)&Xs[idx];
    }
    __builtin_amdgcn_s_setprio(1);
    #pragma unroll
    for (int m=0;m<3;m++)
      #pragma unroll
      for (int mf=0;mf<4;mf++)
        acc[m][mf] = __builtin_amdgcn_mfma_f32_16x16x32_f16(wfr[m], xf[mf], acc[m][mf], 0,0,0);
    __builtin_amdgcn_s_setprio(0);
  }
  const int n0 = (w<<4) + (g<<2);
  #pragma unroll
  for (int m=0;m<3;m++){
    h16* dst = (m==0)?Qh:(m==1)?Kh:Vh;
    #pragma unroll
    for (int mf=0; mf<4; mf++){
      int row = m0 + (mf<<4) + lr;
      f16x4 o;
      #pragma unroll
      for (int i=0;i<4;i++) o[i] = (h16)acc[m][mf][i];
      *(f16x4*)(dst + (size_t)row*128 + n0) = o;
    }
  }
}

// ---------------------------------------------------------------- MFMA attention (inter, r10-verified)
template<int NT, int QG>
__global__ __launch_bounds__(256) void k_attn16(
    const h16* __restrict__ Qh, const h16* __restrict__ Kh, const h16* __restrict__ Vh,
    const float* __restrict__ Resid, float* __restrict__ Out, int hbase){
  __shared__ h16 Ks[64*64];
  __shared__ h16 VsT[64*64];
  __shared__ h16 Ps[4*QG*16*64];
  const int tid = threadIdx.x, lane = tid&63, w = tid>>6;
  const int lr = lane&15, g = lane>>4;
  int hh, t=0, qc=0, s=0;
  if (NT==1){ s = blockIdx.x; hh = blockIdx.y; }
  else      { hh = blockIdx.x; t = blockIdx.y; qc = blockIdx.z; }
  const int ccol = hh<<6;
  const int gcol = (hbase+hh)<<6;

  f16x8 qf[QG][2];
  #pragma unroll
  for (int grp=0; grp<QG; grp++){
    int ql = grp*64 + (w<<4) + lr;
    size_t m = (NT==1) ? ((size_t)s*64 + ql) : (((size_t)qc*(64*QG) + ql)*64 + t);
    const h16* qp = Qh + m*128 + ccol + (g<<3);
    qf[grp][0] = *(const f16x8*)qp;
    qf[grp][1] = *(const f16x8*)(qp + 32);
  }

  f32x4 oc[QG][4];
  float m_r[QG], l_r[QG];
  #pragma unroll
  for (int grp=0; grp<QG; grp++){
    #pragma unroll
    for (int cf=0;cf<4;cf++) oc[grp][cf] = (f32x4){0,0,0,0};
    m_r[grp] = -1e30f; l_r[grp] = 0.f;
  }

  for (int kb=0; kb<NT; kb++){
    __syncthreads();
    #pragma unroll
    for (int it=0; it<2; it++){
      int u = it*256 + tid;
      int row = u>>3, un = u&7;
      size_t m = (NT==1) ? ((size_t)s*64 + row) : (((size_t)kb*64 + row)*64 + t);
      f16x8 kv = *(const f16x8*)(Kh + m*128 + ccol + (un<<3));
      *(f16x8*)&Ks[(row<<6) + ((un ^ (row&7))<<3)] = kv;
      f16x8 vv = *(const f16x8*)(Vh + m*128 + ccol + (un<<3));
      #pragma unroll
      for (int j=0;j<8;j++){
        int d = (un<<3) + j;
        int key = (d + un) & 7;
        VsT[(d<<6) + ((((row>>3) ^ key))<<3) + (row&7)] = vv[j];
      }
    }
    __syncthreads();
    #pragma unroll
    for (int grp=0; grp<QG; grp++){
      f32x4 sa[4];
      #pragma unroll
      for (int mm=0;mm<4;mm++) sa[mm] = (f32x4){0,0,0,0};
      __builtin_amdgcn_s_setprio(1);
      #pragma unroll
      for (int ks=0; ks<2; ks++){
        #pragma unroll
        for (int mm=0;mm<4;mm++){
          int krow = (mm<<4) + lr;
          f16x8 af = *(const f16x8*)&Ks[(krow<<6) + (((g + (ks<<2)) ^ (krow&7))<<3)];
          sa[mm] = __builtin_amdgcn_mfma_f32_16x16x32_f16(af, qf[grp][ks], sa[mm], 0,0,0);
        }
      }
      __builtin_amdgcn_s_setprio(0);
      float pmax = -1e30f;
      #pragma unroll
      for (int mm=0;mm<4;mm++)
        #pragma unroll
        for (int i=0;i<4;i++) pmax = fmaxf(pmax, sa[mm][i]);
      pmax = fmaxf(pmax, __shfl_xor(pmax, 16));
      pmax = fmaxf(pmax, __shfl_xor(pmax, 32));
      float mn = fmaxf(m_r[grp], pmax);
      float sca = __expf(m_r[grp] - mn);
      m_r[grp] = mn;
      float ps = 0.f;
      f16x4 pv[4];
      #pragma unroll
      for (int mm=0;mm<4;mm++){
        #pragma unroll
        for (int i=0;i<4;i++){
          float p = __expf(sa[mm][i] - mn);
          ps += p;
          pv[mm][i] = (h16)p;
        }
      }
      ps += __shfl_xor(ps, 16);
      ps += __shfl_xor(ps, 32);
      l_r[grp] = l_r[grp]*sca + ps;
      const int pbase = ((w*QG + grp)<<10);
      #pragma unroll
      for (int mm=0;mm<4;mm++){
        int k0 = (mm<<4) + (g<<2);
        int unit = k0>>3, off = k0&7;
        *(f16x4*)&Ps[pbase + (lr<<6) + ((unit ^ (lr&7))<<3) + off] = pv[mm];
      }
      #pragma unroll
      for (int i=0;i<4;i++){
        float si = __shfl(sca, (g<<4) + (g<<2) + i);
        #pragma unroll
        for (int cf=0;cf<4;cf++) oc[grp][cf][i] *= si;
      }
      __builtin_amdgcn_s_setprio(1);
      #pragma unroll
      for (int ks=0; ks<2; ks++){
        f16x8 pa = *(const f16x8*)&Ps[pbase + (lr<<6) + (((g + (ks<<2)) ^ (lr&7))<<3)];
        #pragma unroll
        for (int cf=0;cf<4;cf++){
          int d = (cf<<4) + lr;
          int key = (d + (d>>3)) & 7;
          f16x8 bf = *(const f16x8*)&VsT[(d<<6) + (((g + (ks<<2)) ^ key)<<3)];
          oc[grp][cf] = __builtin_amdgcn_mfma_f32_16x16x32_f16(pa, bf, oc[grp][cf], 0,0,0);
        }
      }
      __builtin_amdgcn_s_setprio(0);
    }
  }
  #pragma unroll
  for (int grp=0; grp<QG; grp++){
    float linv = 1.0f/(l_r[grp]*8.0f);
    #pragma unroll
    for (int i=0;i<4;i++){
      float li = __shfl(linv, (g<<4) + (g<<2) + i);
      int ql = grp*64 + (w<<4) + (g<<2) + i;
      size_t m = (NT==1) ? ((size_t)s*64 + ql) : (((size_t)qc*(64*QG) + ql)*64 + t);
      #pragma unroll
      for (int cf=0;cf<4;cf++){
        int d = (cf<<4) + lr;
        size_t ga = m*256 + gcol + d;
        Out[ga] = oc[grp][cf][i]*li + Resid[ga];
      }
    }
  }
}

// ---------------------------------------------------------------- MFMA FFN v5c — r15 + register prefetch
__global__ __launch_bounds__(512,1) void k_ffn5(
    const float* X, float* Out,
    const float* __restrict__ lng, const float* __restrict__ lnb,
    const h16* __restrict__ W1t, const float* __restrict__ b1,
    const h16* __restrict__ W2t, const float* __restrict__ b2){
  __shared__ h16 Xs[64*256];
  __shared__ h16 Hc[64*1024];
  const int tid  = threadIdx.x;
  const int lane = tid & 63;
  const int w    = tid >> 6;
  const int r0   = blockIdx.x << 6;
  const int lr   = lane & 15;
  const int g    = lane >> 4;
  {
    float4 gg = *(const float4*)(lng + (lane<<2));
    float4 bb = *(const float4*)(lnb + (lane<<2));
    #pragma unroll
    for (int rr=0; rr<8; rr++){
      int r = (w<<3) + rr;
      float4 v = *(const float4*)(X + (size_t)(r0+r)*256 + (lane<<2));
      float sm = wave_sum(v.x+v.y+v.z+v.w);
      float sq = wave_sum(v.x*v.x+v.y*v.y+v.z*v.z+v.w*v.w);
      float mean = sm*(1.f/256.f);
      float rs = rsqrtf(sq*(1.f/256.f) - mean*mean + 1e-10f);
      f16x4 o;
      o[0]=(h16)((v.x-mean)*rs*gg.x+bb.x); o[1]=(h16)((v.y-mean)*rs*gg.y+bb.y);
      o[2]=(h16)((v.z-mean)*rs*gg.z+bb.z); o[3]=(h16)((v.w-mean)*rs*gg.w+bb.w);
      int idx = ((r<<8) + (lane<<2)) ^ ((r&7)<<3);
      *(f16x4*)&Xs[idx] = o;
    }
  }
  {
    // GEMM1 swapped with depth-1 prefetch of 8 W-frags
    f32x4 acc1[8][4];
    #pragma unroll
    for (int a=0;a<8;a++)
      #pragma unroll
      for (int b=0;b<4;b++) acc1[a][b] = (f32x4){0,0,0,0};
    f16x8 wp[8];
    #pragma unroll
    for (int nf=0; nf<8; nf++){
      int n = (w<<7) + (nf<<4) + lr;
      wp[nf] = *(const f16x8*)(W1t + (size_t)n*256 + ((w&7)<<5) + (g<<3));
    }
    __syncthreads();   // Xs staged
    #pragma unroll
    for (int i=0; i<8; i++){
      int kt = (i + w) & 7;
      f16x8 xf[4], wfr[8];
      #pragma unroll
      for (int nf=0; nf<8; nf++) wfr[nf] = wp[nf];
      if (i<7){
        int ktn = (i + 1 + w) & 7;
        #pragma unroll
        for (int nf=0; nf<8; nf++){
          int n = (w<<7) + (nf<<4) + lr;
          wp[nf] = *(const f16x8*)(W1t + (size_t)n*256 + (ktn<<5) + (g<<3));
        }
      }
      #pragma unroll
      for (int mf=0; mf<4; mf++){
        int r = (mf<<4) + lr;
        int idx = ((r<<8) + (kt<<5) + (g<<3)) ^ ((r&7)<<3);
        xf[mf] = *(const f16x8*)&Xs[idx];
      }
      __builtin_amdgcn_s_setprio(1);
      #pragma unroll
      for (int nf=0; nf<8; nf++)
        #pragma unroll
        for (int mf=0; mf<4; mf++)
          acc1[nf][mf] = __builtin_amdgcn_mfma_f32_16x16x32_f16(
              wfr[nf], xf[mf], acc1[nf][mf], 0, 0, 0);
      __builtin_amdgcn_s_setprio(0);
    }
    // bias + relu -> Hc, f16x4 along n
    #pragma unroll
    for (int nf=0; nf<8; nf++){
      int n0 = (w<<7) + (nf<<4) + (g<<2);
      float4 bq = *(const float4*)(b1 + n0);
      #pragma unroll
      for (int mf=0; mf<4; mf++){
        int m = (mf<<4) + lr;
        f16x4 o;
        o[0]=(h16)fmaxf(acc1[nf][mf][0]+bq.x,0.f);
        o[1]=(h16)fmaxf(acc1[nf][mf][1]+bq.y,0.f);
        o[2]=(h16)fmaxf(acc1[nf][mf][2]+bq.z,0.f);
        o[3]=(h16)fmaxf(acc1[nf][mf][3]+bq.w,0.f);
        *(f16x4*)&Hc[((m<<10) + n0) ^ ((m&7)<<3)] = o;
      }
    }
  }
  __syncthreads();
  // GEMM2 with depth-2 prefetch
  f32x4 acc2[4][2];
  #pragma unroll
  for (int a=0;a<4;a++){ acc2[a][0]=(f32x4){0,0,0,0}; acc2[a][1]=(f32x4){0,0,0,0}; }
  f16x8 wp2[2][2];
  #pragma unroll
  for (int s=0;s<2;s++){
    int kt = (s + (w<<2)) & 31;
    #pragma unroll
    for (int cf=0;cf<2;cf++){
      int n = (w<<5) + (cf<<4) + lr;
      wp2[s][cf] = *(const f16x8*)(W2t + (size_t)n*1024 + (kt<<5) + (g<<3));
    }
  }
  #pragma unroll
  for (int i=0; i<32; i++){
    const int sl = i&1;
    int kt = (i + (w<<2)) & 31;
    f16x8 af[4], bf[2];
    bf[0] = wp2[sl][0]; bf[1] = wp2[sl][1];
    if (i<30){
      int ktn = ((i+2) + (w<<2)) & 31;
      #pragma unroll
      for (int cf=0;cf<2;cf++){
        int n = (w<<5) + (cf<<4) + lr;
        wp2[sl][cf] = *(const f16x8*)(W2t + (size_t)n*1024 + (ktn<<5) + (g<<3));
      }
    }
    #pragma unroll
    for (int rf=0; rf<4; rf++){
      int r = (rf<<4) + lr;
      int idx = ((r<<10) + (kt<<5) + (g<<3)) ^ ((r&7)<<3);
      af[rf] = *(const f16x8*)&Hc[idx];
    }
    __builtin_amdgcn_s_setprio(1);
    #pragma unroll
    for (int rf=0; rf<4; rf++)
      #pragma unroll
      for (int cf=0; cf<2; cf++)
        acc2[rf][cf] = __builtin_amdgcn_mfma_f32_16x16x32_f16(
            af[rf], bf[cf], acc2[rf][cf], 0, 0, 0);
    __builtin_amdgcn_s_setprio(0);
  }
  #pragma unroll
  for (int cf=0; cf<2; cf++){
    int col = (w<<5) + (cf<<4) + lr;
    float bv = b2[col];
    #pragma unroll
    for (int rf=0; rf<4; rf++){
      #pragma unroll
      for (int i=0;i<4;i++){
        size_t r = (size_t)r0 + (rf<<4) + (g<<2) + i;
        float res = X[r*256 + col];
        Out[r*256 + col] = acc2[rf][cf][i] + bv + res;
      }
    }
  }
}

// ---------------------------------------------------------------- fused head (r13-verified)
__global__ __launch_bounds__(256) void k_head(
    const float* __restrict__ Bb, const h16* __restrict__ Tt,
    const float* __restrict__ predW, const float* __restrict__ predb,
    float* __restrict__ out){
  __shared__ h16 Xs[64*256];
  __shared__ float X1s[64*256];
  __shared__ float lam[64];
  __shared__ float red[4];
  const int tid = threadIdx.x, lane = tid&63, w = tid>>6;
  const int lr = lane&15, g = lane>>4;
  const size_t m0 = (size_t)blockIdx.x<<6;
  #pragma unroll
  for (int it=0; it<16; it++){
    int f4 = it*256 + tid;
    int row = f4>>6, c4 = (f4&63)<<2;
    float4 v = *(const float4*)(Bb + (m0+row)*256 + c4);
    int idx = ((row<<8) + c4) ^ ((row&7)<<3);
    f16x4 o; o[0]=(h16)v.x; o[1]=(h16)v.y; o[2]=(h16)v.z; o[3]=(h16)v.w;
    *(f16x4*)&Xs[idx] = o;
  }
  __syncthreads();
  f32x4 acc[4][4];
  #pragma unroll
  for (int rf=0;rf<4;rf++)
    #pragma unroll
    for (int cf=0;cf<4;cf++) acc[rf][cf] = (f32x4){0,0,0,0};
  #pragma unroll
  for (int kt=0; kt<8; kt++){
    f16x8 af[4], bf[4];
    #pragma unroll
    for (int rf=0; rf<4; rf++){
      int r = (rf<<4) + lr;
      int idx = ((r<<8) + (kt<<5) + (g<<3)) ^ ((r&7)<<3);
      af[rf] = *(const f16x8*)&Xs[idx];
    }
    #pragma unroll
    for (int cf=0; cf<4; cf++){
      int n = (w<<6) + (cf<<4) + lr;
      bf[cf] = *(const f16x8*)(Tt + (size_t)n*256 + (kt<<5) + (g<<3));
    }
    __builtin_amdgcn_s_setprio(1);
    #pragma unroll
    for (int rf=0; rf<4; rf++)
      #pragma unroll
      for (int cf=0; cf<4; cf++)
        acc[rf][cf] = __builtin_amdgcn_mfma_f32_16x16x32_f16(af[rf], bf[cf], acc[rf][cf], 0,0,0);
    __builtin_amdgcn_s_setprio(0);
  }
  #pragma unroll
  for (int cf=0; cf<4; cf++){
    int col = (w<<6) + (cf<<4) + lr;
    #pragma unroll
    for (int rf=0; rf<4; rf++)
      #pragma unroll
      for (int i=0;i<4;i++){
        int r = (rf<<4) + (g<<2) + i;
        X1s[(r<<8) + col] = acc[rf][cf][i];
      }
  }
  __syncthreads();
  float lg[16];
  for (int r=0;r<16;r++){
    int trow = (w<<4) + r;
    float4 xa = *(float4*)&X1s[(trow<<8) + (lane<<2)];
    float4 xc = *(float4*)&X1s[(63<<8) + (lane<<2)];
    lg[r] = wave_sum(xa.x*xc.x + xa.y*xc.y + xa.z*xc.z + xa.w*xc.w);
  }
  if (lane==0){
    #pragma unroll
    for (int r=0;r<16;r++) lam[(w<<4)+r] = lg[r];
  }
  __syncthreads();
  if (tid < 64){
    float v = lam[tid];
    float mx = wave_max(v);
    float p = __expf(v-mx);
    float sm = wave_sum(p);
    lam[tid] = p/sm;
  }
  __syncthreads();
  float ag = 0.f;
  for (int t=0;t<64;t++)
    ag += lam[t]*(float)Xs[((t<<8)+tid) ^ ((t&7)<<3)];
  float wsum = wave_sum(ag * predW[tid]);
  if (lane==0) red[w] = wsum;
  __syncthreads();
  if (tid==0) out[blockIdx.x] = red[0]+red[1]+red[2]+red[3] + predb[0];
}

// ================================================================ launch
extern "C" void kernel_launch(void* const* d_in, const int* in_sizes, int n_in,
                              void* d_out, int out_size, void* d_ws, size_t ws_size,
                              hipStream_t stream){
  const float* x       = (const float*)d_in[0];
  const float* gate_W  = (const float*)d_in[1];
  const float* gate_b  = (const float*)d_in[2];
  const float* embed_W = (const float*)d_in[3];
  const float* ln0_g   = (const float*)d_in[4];
  const float* ln0_b   = (const float*)d_in[5];
  const float* iln_g   = (const float*)d_in[9];
  const float* iln_b   = (const float*)d_in[10];
  const float* iW1     = (const float*)d_in[11];
  const float* ib1     = (const float*)d_in[12];
  const float* iW2     = (const float*)d_in[13];
  const float* ib2     = (const float*)d_in[14];
  const float* eln1_g  = (const float*)d_in[18];
  const float* eln1_b  = (const float*)d_in[19];
  const float* eln2_g  = (const float*)d_in[20];
  const float* eln2_b  = (const float*)d_in[21];
  const float* eW1     = (const float*)d_in[22];
  const float* eb1     = (const float*)d_in[23];
  const float* eW2     = (const float*)d_in[24];
  const float* eb2     = (const float*)d_in[25];
  const float* temp_W  = (const float*)d_in[26];
  const float* pred_W  = (const float*)d_in[27];
  const float* pred_b  = (const float*)d_in[28];
  float* out = (float*)d_out;

  float* pe    = (float*)d_ws;
  float* gate  = pe + 16384;
  h16* fQKV = (h16*)((char*)d_ws + ((size_t)4<<20));
  h16* fE   = fQKV + 393216;
  h16* fT   = fE + 32768;
  h16* fW1i = fT + 65536;
  h16* fW2i = fW1i + 262144;
  h16* fW1e = fW2i + 262144;
  h16* fW2e = fW1e + 262144;
  const size_t MR = (size_t)65536*256, MH = (size_t)65536*128;
  float* A  = (float*)((char*)d_ws + ((size_t)8<<20));
  float* Bb = A + MR;
  h16* Qh = (h16*)(Bb + MR);
  h16* Kh = Qh + MH;
  h16* Vh = Kh + MH;

  k_pe  <<<64,  256, 0, stream>>>(pe);
  k_gate<<<1024, 64, 0, stream>>>(x, gate_W, gate_b, gate);
  k_t16all<<<1504,256,0,stream>>>(
      (const float*)d_in[6],(const float*)d_in[7],(const float*)d_in[8],
      (const float*)d_in[15],(const float*)d_in[16],(const float*)d_in[17],
      embed_W, temp_W, iW1, iW2, eW1, eW2, fQKV);

  // A = LN0(gate*x @ embed_W + pe)
  k_embed<<<1024,256,0,stream>>>(x, fE, pe, gate, ln0_g, ln0_b, A);

  // fused intra QKV+attention: r -> Bb
  k_intra<<<1024,512,0,stream>>>(A, fQKV, Bb);
  k_ffn5<<<1024,512,0,stream>>>(Bb, Bb, iln_g, iln_b, fW1i, ib1, fW2i, ib2);

  // inter attention (transposed batching), LN1 fused into QKV; r2 -> Bb
  for (int hp=0; hp<2; hp++){
    int hb = hp*2;
    k_qkv<true><<<1024,512,0,stream>>>(Bb, eln1_g, eln1_b,
        fQKV + 3*65536 + hb*16384, Qh, Kh, Vh);
    k_attn16<16,1><<<dim3(2,64,16),256,0,stream>>>(Qh, Kh, Vh, Bb, Bb, hb);
  }
  k_ffn5<<<1024,512,0,stream>>>(Bb, Bb, eln2_g, eln2_b, fW1e, eb1, fW2e, eb2);

  // fused head
  k_head<<<1024,256,0,stream>>>(Bb, fT, pred_W, pred_b, out);
}